// Round 1
// baseline (3823.093 us; speedup 1.0000x reference)
//
#include <hip/hip_runtime.h>

#define EMB 600
#define Q4  150   // EMB / 4

__device__ __forceinline__ float4 f4add(float4 a, float4 b) {
    return make_float4(a.x + b.x, a.y + b.y, a.z + b.z, a.w + b.w);
}

// ---------------------------------------------------------------------------
// K1: node embedding = sum of 5 table lookups.  One thread per float4.
// ---------------------------------------------------------------------------
__global__ void k_node_embed(const int* __restrict__ atom,
                             const float4* __restrict__ Wa,
                             const float4* __restrict__ Wh,
                             const float4* __restrict__ War,
                             const float4* __restrict__ Wc,
                             const float4* __restrict__ Wch,
                             float4* __restrict__ out, int N) {
    int idx = blockIdx.x * blockDim.x + threadIdx.x;
    int total = N * Q4;
    if (idx >= total) return;
    int n = idx / Q4;
    int q = idx - n * Q4;
    const int* a = atom + n * 5;
    float4 r = Wa[a[0] * Q4 + q];
    r = f4add(r, Wh [a[1] * Q4 + q]);
    r = f4add(r, War[a[2] * Q4 + q]);
    r = f4add(r, Wc [a[3] * Q4 + q]);
    r = f4add(r, Wch[a[4] * Q4 + q]);
    out[idx] = r;
}

// ---------------------------------------------------------------------------
// K2: one message-passing round.  One 64-lane wave per edge (bonds then
// self-loops).  Edge embedding recomputed on the fly.  Scatter via atomicAdd.
// out must be pre-zeroed.
// ---------------------------------------------------------------------------
__global__ void k_mp(const int* __restrict__ bsrc, const int* __restrict__ bdst,
                     const int* __restrict__ battr, const int* __restrict__ atom,
                     const float4* __restrict__ Wbt, const float4* __restrict__ Wbai,
                     const float4* __restrict__ Wsla, const float4* __restrict__ Wsl,
                     const float4* __restrict__ in, float* __restrict__ out,
                     int E, int N) {
    int wid  = (int)((blockIdx.x * blockDim.x + threadIdx.x) >> 6);
    int lane = threadIdx.x & 63;
    if (wid >= E + N) return;
    int s, d;
    const float4 *e0, *e1;
    if (wid < E) {
        s  = bsrc[wid];
        d  = bdst[wid];
        e0 = Wbt  + battr[wid * 2 + 0] * Q4;
        e1 = Wbai + battr[wid * 2 + 1] * Q4;
    } else {
        int n = wid - E;
        s = n; d = n;
        e0 = Wsla + atom[n * 5] * Q4;
        e1 = Wsl;   // row 0
    }
    const float4* inrow = in + (size_t)s * Q4;
    float* orow = out + (size_t)d * EMB;
    for (int q = lane; q < Q4; q += 64) {
        float4 emb = f4add(e0[q], e1[q]);
        float4 v   = inrow[q];
        float* o = orow + q * 4;
        atomicAdd(o + 0, v.x * emb.x);
        atomicAdd(o + 1, v.y * emb.y);
        atomicAdd(o + 2, v.z * emb.z);
        atomicAdd(o + 3, v.w * emb.w);
    }
}

// ---------------------------------------------------------------------------
// K3: h2 = relu(relu(node) @ W1^T + b1)   [N,600] x [600,600]
// 64x64 tile, BK=8, 256 threads, 4x4 per thread.
// ---------------------------------------------------------------------------
__global__ __launch_bounds__(256) void k_mlp1(const float* __restrict__ A,
                                              const float* __restrict__ W1,
                                              const float* __restrict__ b1,
                                              float* __restrict__ out, int N) {
    __shared__ float As[8][64];
    __shared__ float Bs[8][64];
    int row0 = blockIdx.x * 64;
    int col0 = blockIdx.y * 64;
    int t  = threadIdx.x;
    int tm = t >> 4, tn = t & 15;
    float acc[4][4] = {};
    for (int k0 = 0; k0 < EMB; k0 += 8) {
#pragma unroll
        for (int i = 0; i < 2; i++) {
            int e  = t + i * 256;
            int r  = e >> 3, kk = e & 7;
            int gr = row0 + r;
            float v = (gr < N) ? A[(size_t)gr * EMB + k0 + kk] : 0.f;
            As[kk][r] = fmaxf(v, 0.f);          // relu on load
            int gc = col0 + r;
            Bs[kk][r] = (gc < EMB) ? W1[(size_t)gc * EMB + k0 + kk] : 0.f;
        }
        __syncthreads();
#pragma unroll
        for (int k = 0; k < 8; k++) {
            float4 a4 = *(const float4*)&As[k][tm * 4];
            float4 b4 = *(const float4*)&Bs[k][tn * 4];
            float av[4] = {a4.x, a4.y, a4.z, a4.w};
            float bv[4] = {b4.x, b4.y, b4.z, b4.w};
#pragma unroll
            for (int i = 0; i < 4; i++)
#pragma unroll
                for (int j = 0; j < 4; j++)
                    acc[i][j] += av[i] * bv[j];
        }
        __syncthreads();
    }
#pragma unroll
    for (int i = 0; i < 4; i++) {
        int gr = row0 + tm * 4 + i;
        if (gr >= N) continue;
#pragma unroll
        for (int j = 0; j < 4; j++) {
            int gc = col0 + tn * 4 + j;
            if (gc < EMB)
                out[(size_t)gr * EMB + gc] = fmaxf(acc[i][j] + b1[gc], 0.f);
        }
    }
}

// ---------------------------------------------------------------------------
// K4: energy = relu(h2 @ W2^T + b2) @ W3^T  fused.  [N,600]x[300,600] -> [N]
// ---------------------------------------------------------------------------
__global__ __launch_bounds__(256) void k_mlp2(const float* __restrict__ H,
                                              const float* __restrict__ W2,
                                              const float* __restrict__ b2,
                                              const float* __restrict__ W3,
                                              float* __restrict__ energy, int N) {
    __shared__ float As[8][64];
    __shared__ float Bs[8][64];
    __shared__ float esum[64];
    int row0 = blockIdx.x * 64;
    int t  = threadIdx.x;
    int tm = t >> 4, tn = t & 15;
    if (t < 64) esum[t] = 0.f;
    for (int bn = 0; bn < 5; bn++) {
        int col0 = bn * 64;
        float acc[4][4] = {};
        for (int k0 = 0; k0 < EMB; k0 += 8) {
#pragma unroll
            for (int i = 0; i < 2; i++) {
                int e  = t + i * 256;
                int r  = e >> 3, kk = e & 7;
                int gr = row0 + r;
                As[kk][r] = (gr < N) ? H[(size_t)gr * EMB + k0 + kk] : 0.f;
                int gc = col0 + r;
                Bs[kk][r] = (gc < 300) ? W2[(size_t)gc * EMB + k0 + kk] : 0.f;
            }
            __syncthreads();
#pragma unroll
            for (int k = 0; k < 8; k++) {
                float4 a4 = *(const float4*)&As[k][tm * 4];
                float4 b4 = *(const float4*)&Bs[k][tn * 4];
                float av[4] = {a4.x, a4.y, a4.z, a4.w};
                float bv[4] = {b4.x, b4.y, b4.z, b4.w};
#pragma unroll
                for (int i = 0; i < 4; i++)
#pragma unroll
                    for (int j = 0; j < 4; j++)
                        acc[i][j] += av[i] * bv[j];
            }
            __syncthreads();
        }
#pragma unroll
        for (int i = 0; i < 4; i++) {
            float rs = 0.f;
#pragma unroll
            for (int j = 0; j < 4; j++) {
                int gc = col0 + tn * 4 + j;
                if (gc < 300)
                    rs += fmaxf(acc[i][j] + b2[gc], 0.f) * W3[gc];
            }
            atomicAdd(&esum[tm * 4 + i], rs);
        }
        __syncthreads();
    }
    if (t < 64 && row0 + t < N) energy[row0 + t] = esum[t];
}

// ---------------------------------------------------------------------------
// K5: per-graph pool
// ---------------------------------------------------------------------------
__global__ void k_pool(const float* __restrict__ energy, const int* __restrict__ batch,
                       float* __restrict__ dg, int N) {
    int i = blockIdx.x * blockDim.x + threadIdx.x;
    if (i < N) atomicAdd(&dg[batch[i]], energy[i]);
}

extern "C" void kernel_launch(void* const* d_in, const int* in_sizes, int n_in,
                              void* d_out, int out_size, void* d_ws, size_t ws_size,
                              hipStream_t stream) {
    const int* atom       = (const int*)d_in[0];
    const int* bond_index = (const int*)d_in[1];
    const int* bond_attr  = (const int*)d_in[2];
    const int* batch      = (const int*)d_in[3];
    const float* Wa   = (const float*)d_in[4];
    const float* Wh   = (const float*)d_in[5];
    const float* War  = (const float*)d_in[6];
    const float* Wc   = (const float*)d_in[7];
    const float* Wch  = (const float*)d_in[8];
    const float* Wbt  = (const float*)d_in[9];
    const float* Wbai = (const float*)d_in[10];
    const float* Wsla = (const float*)d_in[11];
    const float* Wsl  = (const float*)d_in[12];
    const float* W1   = (const float*)d_in[13];
    const float* b1   = (const float*)d_in[14];
    const float* W2   = (const float*)d_in[15];
    const float* b2   = (const float*)d_in[16];
    const float* W3   = (const float*)d_in[17];

    int N = in_sizes[0] / 5;   // 50000
    int E = in_sizes[1] / 2;   // 100000

    float* bufA   = (float*)d_ws;
    float* bufB   = bufA + (size_t)N * EMB;
    float* energy = bufB + (size_t)N * EMB;

    // K1: node embedding -> bufA
    {
        int total = N * Q4;
        k_node_embed<<<(total + 255) / 256, 256, 0, stream>>>(
            atom, (const float4*)Wa, (const float4*)Wh, (const float4*)War,
            (const float4*)Wc, (const float4*)Wch, (float4*)bufA, N);
    }

    int nwaves   = E + N;
    int mpblocks = (nwaves * 64 + 255) / 256;

    // round 1: A -> B
    hipMemsetAsync(bufB, 0, (size_t)N * EMB * sizeof(float), stream);
    k_mp<<<mpblocks, 256, 0, stream>>>(bond_index, bond_index + E, bond_attr, atom,
                                       (const float4*)Wbt, (const float4*)Wbai,
                                       (const float4*)Wsla, (const float4*)Wsl,
                                       (const float4*)bufA, bufB, E, N);
    // round 2: B -> A
    hipMemsetAsync(bufA, 0, (size_t)N * EMB * sizeof(float), stream);
    k_mp<<<mpblocks, 256, 0, stream>>>(bond_index, bond_index + E, bond_attr, atom,
                                       (const float4*)Wbt, (const float4*)Wbai,
                                       (const float4*)Wsla, (const float4*)Wsl,
                                       (const float4*)bufB, bufA, E, N);

    // K3: layer 1 (A -> B)
    {
        dim3 grid((N + 63) / 64, (EMB + 63) / 64);
        k_mlp1<<<grid, 256, 0, stream>>>(bufA, W1, b1, bufB, N);
    }
    // K4: layers 2+3 fused (B -> energy)
    k_mlp2<<<(N + 63) / 64, 256, 0, stream>>>(bufB, W2, b2, W3, energy, N);

    // K5: pool
    hipMemsetAsync(d_out, 0, (size_t)out_size * sizeof(float), stream);
    k_pool<<<(N + 255) / 256, 256, 0, stream>>>(energy, batch, (float*)d_out, N);
}

// Round 2
// 1544.710 us; speedup vs baseline: 2.4750x; 2.4750x over previous
//
#include <hip/hip_runtime.h>

#define EMB 600
#define Q4  150   // EMB / 4

__device__ __forceinline__ float4 f4add(float4 a, float4 b) {
    return make_float4(a.x + b.x, a.y + b.y, a.z + b.z, a.w + b.w);
}
__device__ __forceinline__ float4 f4fma(float4 acc, float4 v, float4 e) {
    return make_float4(fmaf(v.x, e.x, acc.x), fmaf(v.y, e.y, acc.y),
                       fmaf(v.z, e.z, acc.z), fmaf(v.w, e.w, acc.w));
}

// ---------------------------------------------------------------------------
// K1: node embedding = sum of 5 table lookups.  One thread per float4.
// ---------------------------------------------------------------------------
__global__ void k_node_embed(const int* __restrict__ atom,
                             const float4* __restrict__ Wa,
                             const float4* __restrict__ Wh,
                             const float4* __restrict__ War,
                             const float4* __restrict__ Wc,
                             const float4* __restrict__ Wch,
                             float4* __restrict__ out, int N) {
    int idx = blockIdx.x * blockDim.x + threadIdx.x;
    int total = N * Q4;
    if (idx >= total) return;
    int n = idx / Q4;
    int q = idx - n * Q4;
    const int* a = atom + n * 5;
    float4 r = Wa[a[0] * Q4 + q];
    r = f4add(r, Wh [a[1] * Q4 + q]);
    r = f4add(r, War[a[2] * Q4 + q]);
    r = f4add(r, Wc [a[3] * Q4 + q]);
    r = f4add(r, Wch[a[4] * Q4 + q]);
    out[idx] = r;
}

// ---------------------------------------------------------------------------
// CSR build: histogram -> scan -> scatter
// ---------------------------------------------------------------------------
__global__ void k_hist(const int* __restrict__ bdst, int* __restrict__ counts, int E) {
    int i = blockIdx.x * blockDim.x + threadIdx.x;
    if (i < E) atomicAdd(&counts[bdst[i]], 1);
}

// single-workgroup exclusive scan of counts[N] -> offsets[N] (+ cursor copy)
__global__ __launch_bounds__(1024) void k_scan(const int* __restrict__ counts,
                                               int* __restrict__ offsets,
                                               int* __restrict__ cursor, int N) {
    __shared__ int sums[1024];
    int t = threadIdx.x;
    int chunk = (N + 1023) / 1024;
    int begin = t * chunk;
    int end = begin + chunk; if (end > N) end = N;
    int s = 0;
    for (int i = begin; i < end; i++) s += counts[i];
    sums[t] = s;
    __syncthreads();
    for (int off = 1; off < 1024; off <<= 1) {
        int v = (t >= off) ? sums[t - off] : 0;
        __syncthreads();
        sums[t] += v;
        __syncthreads();
    }
    int run = (t == 0) ? 0 : sums[t - 1];
    for (int i = begin; i < end; i++) {
        offsets[i] = run;
        cursor[i]  = run;
        run += counts[i];
    }
}

__global__ void k_scatter(const int* __restrict__ bdst, int* __restrict__ cursor,
                          int* __restrict__ edge_list, int E) {
    int i = blockIdx.x * blockDim.x + threadIdx.x;
    if (i < E) {
        int pos = atomicAdd(&cursor[bdst[i]], 1);
        edge_list[pos] = i;
    }
}

// ---------------------------------------------------------------------------
// K2: one message-passing round, CSR gather form.  One wave per dest node.
// acc initialized with the self-loop term; then walk incoming bond edges.
// ---------------------------------------------------------------------------
__global__ __launch_bounds__(256) void k_mp_gather(
        const int* __restrict__ bsrc, const int* __restrict__ battr,
        const int* __restrict__ atom,
        const int* __restrict__ offsets, const int* __restrict__ counts,
        const int* __restrict__ edge_list,
        const float4* __restrict__ Wbt, const float4* __restrict__ Wbai,
        const float4* __restrict__ Wsla, const float4* __restrict__ Wsl,
        const float4* __restrict__ in, float4* __restrict__ out, int N) {
    int wid  = (int)((blockIdx.x * blockDim.x + threadIdx.x) >> 6);
    int lane = threadIdx.x & 63;
    if (wid >= N) return;
    int d = wid;
    int q0 = lane, q1 = lane + 64, q2 = lane + 128;
    bool has2 = (q2 < Q4);

    // self-loop term
    const float4* slA = Wsla + atom[d * 5] * Q4;
    const float4* inr = in + (size_t)d * Q4;
    float4 acc0 = make_float4(0, 0, 0, 0), acc1 = acc0, acc2 = acc0;
    acc0 = f4fma(acc0, inr[q0], f4add(slA[q0], Wsl[q0]));
    acc1 = f4fma(acc1, inr[q1], f4add(slA[q1], Wsl[q1]));
    if (has2) acc2 = f4fma(acc2, inr[q2], f4add(slA[q2], Wsl[q2]));

    int start = offsets[d], cnt = counts[d];
    for (int k = 0; k < cnt; k++) {
        int eid = edge_list[start + k];
        int s   = bsrc[eid];
        int t0  = battr[eid * 2 + 0];
        int t1  = battr[eid * 2 + 1];
        const float4* e0 = Wbt  + t0 * Q4;
        const float4* e1 = Wbai + t1 * Q4;
        const float4* sr = in + (size_t)s * Q4;
        acc0 = f4fma(acc0, sr[q0], f4add(e0[q0], e1[q0]));
        acc1 = f4fma(acc1, sr[q1], f4add(e0[q1], e1[q1]));
        if (has2) acc2 = f4fma(acc2, sr[q2], f4add(e0[q2], e1[q2]));
    }
    float4* orow = out + (size_t)d * Q4;
    orow[q0] = acc0;
    orow[q1] = acc1;
    if (has2) orow[q2] = acc2;
}

// ---------------------------------------------------------------------------
// K3: h2 = relu(relu(node) @ W1^T + b1)   [N,600] x [600,600]
// ---------------------------------------------------------------------------
__global__ __launch_bounds__(256) void k_mlp1(const float* __restrict__ A,
                                              const float* __restrict__ W1,
                                              const float* __restrict__ b1,
                                              float* __restrict__ out, int N) {
    __shared__ float As[8][64];
    __shared__ float Bs[8][64];
    int row0 = blockIdx.x * 64;
    int col0 = blockIdx.y * 64;
    int t  = threadIdx.x;
    int tm = t >> 4, tn = t & 15;
    float acc[4][4] = {};
    for (int k0 = 0; k0 < EMB; k0 += 8) {
#pragma unroll
        for (int i = 0; i < 2; i++) {
            int e  = t + i * 256;
            int r  = e >> 3, kk = e & 7;
            int gr = row0 + r;
            float v = (gr < N) ? A[(size_t)gr * EMB + k0 + kk] : 0.f;
            As[kk][r] = fmaxf(v, 0.f);          // relu on load
            int gc = col0 + r;
            Bs[kk][r] = (gc < EMB) ? W1[(size_t)gc * EMB + k0 + kk] : 0.f;
        }
        __syncthreads();
#pragma unroll
        for (int k = 0; k < 8; k++) {
            float4 a4 = *(const float4*)&As[k][tm * 4];
            float4 b4 = *(const float4*)&Bs[k][tn * 4];
            float av[4] = {a4.x, a4.y, a4.z, a4.w};
            float bv[4] = {b4.x, b4.y, b4.z, b4.w};
#pragma unroll
            for (int i = 0; i < 4; i++)
#pragma unroll
                for (int j = 0; j < 4; j++)
                    acc[i][j] += av[i] * bv[j];
        }
        __syncthreads();
    }
#pragma unroll
    for (int i = 0; i < 4; i++) {
        int gr = row0 + tm * 4 + i;
        if (gr >= N) continue;
#pragma unroll
        for (int j = 0; j < 4; j++) {
            int gc = col0 + tn * 4 + j;
            if (gc < EMB)
                out[(size_t)gr * EMB + gc] = fmaxf(acc[i][j] + b1[gc], 0.f);
        }
    }
}

// ---------------------------------------------------------------------------
// K4: energy = relu(h2 @ W2^T + b2) @ W3^T  fused.  [N,600]x[300,600] -> [N]
// ---------------------------------------------------------------------------
__global__ __launch_bounds__(256) void k_mlp2(const float* __restrict__ H,
                                              const float* __restrict__ W2,
                                              const float* __restrict__ b2,
                                              const float* __restrict__ W3,
                                              float* __restrict__ energy, int N) {
    __shared__ float As[8][64];
    __shared__ float Bs[8][64];
    __shared__ float esum[64];
    int row0 = blockIdx.x * 64;
    int t  = threadIdx.x;
    int tm = t >> 4, tn = t & 15;
    if (t < 64) esum[t] = 0.f;
    for (int bn = 0; bn < 5; bn++) {
        int col0 = bn * 64;
        float acc[4][4] = {};
        for (int k0 = 0; k0 < EMB; k0 += 8) {
#pragma unroll
            for (int i = 0; i < 2; i++) {
                int e  = t + i * 256;
                int r  = e >> 3, kk = e & 7;
                int gr = row0 + r;
                As[kk][r] = (gr < N) ? H[(size_t)gr * EMB + k0 + kk] : 0.f;
                int gc = col0 + r;
                Bs[kk][r] = (gc < 300) ? W2[(size_t)gc * EMB + k0 + kk] : 0.f;
            }
            __syncthreads();
#pragma unroll
            for (int k = 0; k < 8; k++) {
                float4 a4 = *(const float4*)&As[k][tm * 4];
                float4 b4 = *(const float4*)&Bs[k][tn * 4];
                float av[4] = {a4.x, a4.y, a4.z, a4.w};
                float bv[4] = {b4.x, b4.y, b4.z, b4.w};
#pragma unroll
                for (int i = 0; i < 4; i++)
#pragma unroll
                    for (int j = 0; j < 4; j++)
                        acc[i][j] += av[i] * bv[j];
            }
            __syncthreads();
        }
#pragma unroll
        for (int i = 0; i < 4; i++) {
            float rs = 0.f;
#pragma unroll
            for (int j = 0; j < 4; j++) {
                int gc = col0 + tn * 4 + j;
                if (gc < 300)
                    rs += fmaxf(acc[i][j] + b2[gc], 0.f) * W3[gc];
            }
            atomicAdd(&esum[tm * 4 + i], rs);
        }
        __syncthreads();
    }
    if (t < 64 && row0 + t < N) energy[row0 + t] = esum[t];
}

// ---------------------------------------------------------------------------
// K5: per-graph pool
// ---------------------------------------------------------------------------
__global__ void k_pool(const float* __restrict__ energy, const int* __restrict__ batch,
                       float* __restrict__ dg, int N) {
    int i = blockIdx.x * blockDim.x + threadIdx.x;
    if (i < N) atomicAdd(&dg[batch[i]], energy[i]);
}

extern "C" void kernel_launch(void* const* d_in, const int* in_sizes, int n_in,
                              void* d_out, int out_size, void* d_ws, size_t ws_size,
                              hipStream_t stream) {
    const int* atom       = (const int*)d_in[0];
    const int* bond_index = (const int*)d_in[1];
    const int* bond_attr  = (const int*)d_in[2];
    const int* batch      = (const int*)d_in[3];
    const float* Wa   = (const float*)d_in[4];
    const float* Wh   = (const float*)d_in[5];
    const float* War  = (const float*)d_in[6];
    const float* Wc   = (const float*)d_in[7];
    const float* Wch  = (const float*)d_in[8];
    const float* Wbt  = (const float*)d_in[9];
    const float* Wbai = (const float*)d_in[10];
    const float* Wsla = (const float*)d_in[11];
    const float* Wsl  = (const float*)d_in[12];
    const float* W1   = (const float*)d_in[13];
    const float* b1   = (const float*)d_in[14];
    const float* W2   = (const float*)d_in[15];
    const float* b2   = (const float*)d_in[16];
    const float* W3   = (const float*)d_in[17];

    int N = in_sizes[0] / 5;   // 50000
    int E = in_sizes[1] / 2;   // 100000

    float* bufA   = (float*)d_ws;
    float* bufB   = bufA + (size_t)N * EMB;
    float* energy = bufB + (size_t)N * EMB;
    int* counts    = (int*)(energy + N);
    int* offsets   = counts + N;
    int* cursor    = offsets + N;
    int* edge_list = cursor + N;

    const int* bsrc = bond_index;
    const int* bdst = bond_index + E;

    // CSR build (dst -> edges)
    hipMemsetAsync(counts, 0, (size_t)N * sizeof(int), stream);
    k_hist<<<(E + 255) / 256, 256, 0, stream>>>(bdst, counts, E);
    k_scan<<<1, 1024, 0, stream>>>(counts, offsets, cursor, N);
    k_scatter<<<(E + 255) / 256, 256, 0, stream>>>(bdst, cursor, edge_list, E);

    // K1: node embedding -> bufA
    {
        int total = N * Q4;
        k_node_embed<<<(total + 255) / 256, 256, 0, stream>>>(
            atom, (const float4*)Wa, (const float4*)Wh, (const float4*)War,
            (const float4*)Wc, (const float4*)Wch, (float4*)bufA, N);
    }

    int mpblocks = (N * 64 + 255) / 256;
    // round 1: A -> B
    k_mp_gather<<<mpblocks, 256, 0, stream>>>(bsrc, bond_attr, atom,
        offsets, counts, edge_list,
        (const float4*)Wbt, (const float4*)Wbai, (const float4*)Wsla, (const float4*)Wsl,
        (const float4*)bufA, (float4*)bufB, N);
    // round 2: B -> A
    k_mp_gather<<<mpblocks, 256, 0, stream>>>(bsrc, bond_attr, atom,
        offsets, counts, edge_list,
        (const float4*)Wbt, (const float4*)Wbai, (const float4*)Wsla, (const float4*)Wsl,
        (const float4*)bufB, (float4*)bufA, N);

    // K3: layer 1 (A -> B)
    {
        dim3 grid((N + 63) / 64, (EMB + 63) / 64);
        k_mlp1<<<grid, 256, 0, stream>>>(bufA, W1, b1, bufB, N);
    }
    // K4: layers 2+3 fused (B -> energy)
    k_mlp2<<<(N + 63) / 64, 256, 0, stream>>>(bufB, W2, b2, W3, energy, N);

    // K5: pool
    hipMemsetAsync(d_out, 0, (size_t)out_size * sizeof(float), stream);
    k_pool<<<(N + 255) / 256, 256, 0, stream>>>(energy, batch, (float*)d_out, N);
}

// Round 3
// 1226.295 us; speedup vs baseline: 3.1176x; 1.2597x over previous
//
#include <hip/hip_runtime.h>

#define EMB 600
#define Q4  150   // EMB / 4

typedef unsigned short ushortT;
typedef __attribute__((ext_vector_type(8))) short short8;
typedef __attribute__((ext_vector_type(4))) float f32x4;

__device__ __forceinline__ float4 f4add(float4 a, float4 b) {
    return make_float4(a.x + b.x, a.y + b.y, a.z + b.z, a.w + b.w);
}
__device__ __forceinline__ float4 f4fma(float4 acc, float4 v, float4 e) {
    return make_float4(fmaf(v.x, e.x, acc.x), fmaf(v.y, e.y, acc.y),
                       fmaf(v.z, e.z, acc.z), fmaf(v.w, e.w, acc.w));
}

__device__ __forceinline__ ushortT bf16_rne(float x) {
    unsigned u = __float_as_uint(x);
    return (ushortT)((u + 0x7fffu + ((u >> 16) & 1u)) >> 16);
}
__device__ __forceinline__ float bf16_to_f(ushortT h) {
    return __uint_as_float(((unsigned)h) << 16);
}

// ---------------------------------------------------------------------------
// K1: node embedding = sum of 5 table lookups.
// ---------------------------------------------------------------------------
__global__ void k_node_embed(const int* __restrict__ atom,
                             const float4* __restrict__ Wa,
                             const float4* __restrict__ Wh,
                             const float4* __restrict__ War,
                             const float4* __restrict__ Wc,
                             const float4* __restrict__ Wch,
                             float4* __restrict__ out, int N) {
    int idx = blockIdx.x * blockDim.x + threadIdx.x;
    int total = N * Q4;
    if (idx >= total) return;
    int n = idx / Q4;
    int q = idx - n * Q4;
    const int* a = atom + n * 5;
    float4 r = Wa[a[0] * Q4 + q];
    r = f4add(r, Wh [a[1] * Q4 + q]);
    r = f4add(r, War[a[2] * Q4 + q]);
    r = f4add(r, Wc [a[3] * Q4 + q]);
    r = f4add(r, Wch[a[4] * Q4 + q]);
    out[idx] = r;
}

// ---------------------------------------------------------------------------
// CSR build: histogram -> scan -> scatter
// ---------------------------------------------------------------------------
__global__ void k_hist(const int* __restrict__ bdst, int* __restrict__ counts, int E) {
    int i = blockIdx.x * blockDim.x + threadIdx.x;
    if (i < E) atomicAdd(&counts[bdst[i]], 1);
}

__global__ __launch_bounds__(1024) void k_scan(const int* __restrict__ counts,
                                               int* __restrict__ offsets,
                                               int* __restrict__ cursor, int N) {
    __shared__ int sums[1024];
    int t = threadIdx.x;
    int chunk = (N + 1023) / 1024;
    int begin = t * chunk;
    int end = begin + chunk; if (end > N) end = N;
    int s = 0;
    for (int i = begin; i < end; i++) s += counts[i];
    sums[t] = s;
    __syncthreads();
    for (int off = 1; off < 1024; off <<= 1) {
        int v = (t >= off) ? sums[t - off] : 0;
        __syncthreads();
        sums[t] += v;
        __syncthreads();
    }
    int run = (t == 0) ? 0 : sums[t - 1];
    for (int i = begin; i < end; i++) {
        offsets[i] = run;
        cursor[i]  = run;
        run += counts[i];
    }
}

__global__ void k_scatter(const int* __restrict__ bdst, int* __restrict__ cursor,
                          int* __restrict__ edge_list, int E) {
    int i = blockIdx.x * blockDim.x + threadIdx.x;
    if (i < E) {
        int pos = atomicAdd(&cursor[bdst[i]], 1);
        edge_list[pos] = i;
    }
}

// ---------------------------------------------------------------------------
// K2: message-passing round, CSR gather form. One wave per dest node.
// ---------------------------------------------------------------------------
__global__ __launch_bounds__(256) void k_mp_gather(
        const int* __restrict__ bsrc, const int* __restrict__ battr,
        const int* __restrict__ atom,
        const int* __restrict__ offsets, const int* __restrict__ counts,
        const int* __restrict__ edge_list,
        const float4* __restrict__ Wbt, const float4* __restrict__ Wbai,
        const float4* __restrict__ Wsla, const float4* __restrict__ Wsl,
        const float4* __restrict__ in, float4* __restrict__ out, int N) {
    int wid  = (int)((blockIdx.x * blockDim.x + threadIdx.x) >> 6);
    int lane = threadIdx.x & 63;
    if (wid >= N) return;
    int d = wid;
    int q0 = lane, q1 = lane + 64, q2 = lane + 128;
    bool has2 = (q2 < Q4);

    const float4* slA = Wsla + atom[d * 5] * Q4;
    const float4* inr = in + (size_t)d * Q4;
    float4 acc0 = make_float4(0, 0, 0, 0), acc1 = acc0, acc2 = acc0;
    acc0 = f4fma(acc0, inr[q0], f4add(slA[q0], Wsl[q0]));
    acc1 = f4fma(acc1, inr[q1], f4add(slA[q1], Wsl[q1]));
    if (has2) acc2 = f4fma(acc2, inr[q2], f4add(slA[q2], Wsl[q2]));

    int start = offsets[d], cnt = counts[d];
    for (int k = 0; k < cnt; k++) {
        int eid = edge_list[start + k];
        int s   = bsrc[eid];
        int t0  = battr[eid * 2 + 0];
        int t1  = battr[eid * 2 + 1];
        const float4* e0 = Wbt  + t0 * Q4;
        const float4* e1 = Wbai + t1 * Q4;
        const float4* sr = in + (size_t)s * Q4;
        acc0 = f4fma(acc0, sr[q0], f4add(e0[q0], e1[q0]));
        acc1 = f4fma(acc1, sr[q1], f4add(e0[q1], e1[q1]));
        if (has2) acc2 = f4fma(acc2, sr[q2], f4add(e0[q2], e1[q2]));
    }
    float4* orow = out + (size_t)d * Q4;
    orow[q0] = acc0;
    orow[q1] = acc1;
    if (has2) orow[q2] = acc2;
}

// ---------------------------------------------------------------------------
// Split kernels: fp32 -> (bf16 hi, bf16 lo)
// ---------------------------------------------------------------------------
// activations: relu(bufA[N][600]) -> Ahi/Alo [N][600] bf16
__global__ void k_split_relu(const float* __restrict__ src,
                             ushortT* __restrict__ hi, ushortT* __restrict__ lo,
                             int N) {
    int idx = blockIdx.x * blockDim.x + threadIdx.x;
    int total = N * 75;                  // 75 ushort8 units per row
    if (idx >= total) return;
    const float* p = src + (size_t)idx * 8;
    ushortT h[8], l[8];
#pragma unroll
    for (int j = 0; j < 8; j++) {
        float x = fmaxf(p[j], 0.f);
        ushortT hh = bf16_rne(x);
        h[j] = hh;
        l[j] = bf16_rne(x - bf16_to_f(hh));
    }
    *(short8*)(hi + (size_t)idx * 8) = *(short8*)h;
    *(short8*)(lo + (size_t)idx * 8) = *(short8*)l;
}

// weights: src[rows_in][600] -> hi/lo [rows_out][608], zero-padded
__global__ void k_split_w(const float* __restrict__ src,
                          ushortT* __restrict__ hi, ushortT* __restrict__ lo,
                          int rows_in, int rows_out) {
    int idx = blockIdx.x * blockDim.x + threadIdx.x;
    int total = rows_out * 76;           // 76 ushort8 units per padded row
    if (idx >= total) return;
    int row = idx / 76;
    int u   = idx - row * 76;
    ushortT h[8], l[8];
    if (row < rows_in && u < 75) {
        const float* p = src + (size_t)row * 600 + u * 8;
#pragma unroll
        for (int j = 0; j < 8; j++) {
            float x = p[j];
            ushortT hh = bf16_rne(x);
            h[j] = hh;
            l[j] = bf16_rne(x - bf16_to_f(hh));
        }
    } else {
#pragma unroll
        for (int j = 0; j < 8; j++) { h[j] = 0; l[j] = 0; }
    }
    *(short8*)(hi + (size_t)row * 608 + u * 8) = *(short8*)h;
    *(short8*)(lo + (size_t)row * 608 + u * 8) = *(short8*)l;
}

// ---------------------------------------------------------------------------
// MFMA GEMM core (bf16x3): block = 64 rows x (19 col-tiles of 16), K = 600
// (padded to 608, chunks of 64 staged in LDS). 256 threads = 4 waves, each
// wave owns a 16-row strip. A layout [N][600] bf16 hi/lo, W layout
// [608-ish][608] bf16 hi/lo (row = output col, padded with zeros).
// ---------------------------------------------------------------------------
#define LDSP 72   // LDS pitch in ushort (odd dword stride -> conflict-free-ish)

__device__ __forceinline__ void gemm_core(
        const ushortT* __restrict__ Ahi, const ushortT* __restrict__ Alo,
        const ushortT* __restrict__ Whi, const ushortT* __restrict__ Wlo,
        int n0, int row0, int N, f32x4* acc,
        ushortT* sAhi, ushortT* sAlo) {
    int t = threadIdx.x;
    int w = t >> 6;
    int l = t & 63;
    int srow = t >> 2;           // 0..63
    int part = t & 3;            // 0..3, 2 ushort8 units each
    int gr = row0 + srow;
    const ushortT* arow_hi = Ahi + (size_t)gr * 600;
    const ushortT* arow_lo = Alo + (size_t)gr * 600;
    int lrow = (w * 16 + (l & 15)) * LDSP;
    int kgrp = (l >> 4) * 8;
    const short8 zero8 = short8{0,0,0,0,0,0,0,0};

    for (int kc = 0; kc < 10; kc++) {
        // ---- stage A chunk (64 rows x 64 k) hi/lo into LDS ----
#pragma unroll
        for (int j = 0; j < 2; j++) {
            int u = kc * 8 + part * 2 + j;           // ushort8 unit in row
            bool valid = (gr < N) && (u < 75);
            short8 vh = valid ? *(const short8*)(arow_hi + u * 8) : zero8;
            short8 vl = valid ? *(const short8*)(arow_lo + u * 8) : zero8;
            int lo_off = srow * LDSP + (part * 2 + j) * 8;
            *(short8*)&sAhi[lo_off] = vh;
            *(short8*)&sAlo[lo_off] = vl;
        }
        __syncthreads();
        int nks = (kc == 9) ? 1 : 2;                 // last chunk: only k 576..607
        for (int ks = 0; ks < nks; ks++) {
            int koff = ks * 32 + kgrp;
            short8 ah = *(short8*)&sAhi[lrow + koff];
            short8 al = *(short8*)&sAlo[lrow + koff];
            int kglob = kc * 64 + koff;
            const ushortT* pbh = Whi + (size_t)(n0 + (l & 15)) * 608 + kglob;
            const ushortT* pbl = Wlo + (size_t)(n0 + (l & 15)) * 608 + kglob;
#pragma unroll
            for (int ct = 0; ct < 19; ct++) {
                short8 bh = *(const short8*)(pbh + (size_t)ct * 16 * 608);
                short8 bl = *(const short8*)(pbl + (size_t)ct * 16 * 608);
                acc[ct] = __builtin_amdgcn_mfma_f32_16x16x32_bf16(ah, bh, acc[ct], 0, 0, 0);
                acc[ct] = __builtin_amdgcn_mfma_f32_16x16x32_bf16(ah, bl, acc[ct], 0, 0, 0);
                acc[ct] = __builtin_amdgcn_mfma_f32_16x16x32_bf16(al, bh, acc[ct], 0, 0, 0);
            }
        }
        __syncthreads();
    }
}

// GEMM1: h1 = relu(A @ W1^T + b1), written as bf16 hi/lo. grid (Mb, 2).
__global__ __launch_bounds__(256) void k_gemm1(
        const ushortT* __restrict__ Ahi, const ushortT* __restrict__ Alo,
        const ushortT* __restrict__ Whi, const ushortT* __restrict__ Wlo,
        const float* __restrict__ b1,
        ushortT* __restrict__ Hhi, ushortT* __restrict__ Hlo, int N) {
    __shared__ ushortT sAhi[64 * LDSP];
    __shared__ ushortT sAlo[64 * LDSP];
    int row0 = blockIdx.x * 64;
    int n0   = blockIdx.y * 304;
    f32x4 acc[19];
#pragma unroll
    for (int ct = 0; ct < 19; ct++) acc[ct] = f32x4{0.f, 0.f, 0.f, 0.f};
    gemm_core(Ahi, Alo, Whi, Wlo, n0, row0, N, acc, sAhi, sAlo);

    int t = threadIdx.x, w = t >> 6, l = t & 63;
#pragma unroll
    for (int ct = 0; ct < 19; ct++) {
        int col = n0 + ct * 16 + (l & 15);
        if (col >= 600) continue;
        float bias = b1[col];
#pragma unroll
        for (int reg = 0; reg < 4; reg++) {
            int row = row0 + w * 16 + (l >> 4) * 4 + reg;
            if (row >= N) continue;
            float x = fmaxf(acc[ct][reg] + bias, 0.f);
            ushortT hh = bf16_rne(x);
            ushortT ll = bf16_rne(x - bf16_to_f(hh));
            Hhi[(size_t)row * 600 + col] = hh;
            Hlo[(size_t)row * 600 + col] = ll;
        }
    }
}

// GEMM2: energy = (relu(H @ W2^T + b2)) @ W3^T, fused. grid (Mb).
__global__ __launch_bounds__(256) void k_gemm2(
        const ushortT* __restrict__ Ahi, const ushortT* __restrict__ Alo,
        const ushortT* __restrict__ Whi, const ushortT* __restrict__ Wlo,
        const float* __restrict__ b2, const float* __restrict__ W3,
        float* __restrict__ energy, int N) {
    __shared__ ushortT sAhi[64 * LDSP];
    __shared__ ushortT sAlo[64 * LDSP];
    int row0 = blockIdx.x * 64;
    f32x4 acc[19];
#pragma unroll
    for (int ct = 0; ct < 19; ct++) acc[ct] = f32x4{0.f, 0.f, 0.f, 0.f};
    gemm_core(Ahi, Alo, Whi, Wlo, 0, row0, N, acc, sAhi, sAlo);

    int t = threadIdx.x, w = t >> 6, l = t & 63;
    float ep[4] = {0.f, 0.f, 0.f, 0.f};
#pragma unroll
    for (int ct = 0; ct < 19; ct++) {
        int col = ct * 16 + (l & 15);
        if (col >= 300) continue;
        float bias = b2[col];
        float w3   = W3[col];
#pragma unroll
        for (int reg = 0; reg < 4; reg++)
            ep[reg] += fmaxf(acc[ct][reg] + bias, 0.f) * w3;
    }
    // reduce across the 16 lanes that share each row group
#pragma unroll
    for (int reg = 0; reg < 4; reg++) {
        float v = ep[reg];
        v += __shfl_xor(v, 1, 64);
        v += __shfl_xor(v, 2, 64);
        v += __shfl_xor(v, 4, 64);
        v += __shfl_xor(v, 8, 64);
        ep[reg] = v;
    }
    if ((l & 15) == 0) {
#pragma unroll
        for (int reg = 0; reg < 4; reg++) {
            int row = row0 + w * 16 + (l >> 4) * 4 + reg;
            if (row < N) energy[row] = ep[reg];
        }
    }
}

// ---------------------------------------------------------------------------
// K5: per-graph pool
// ---------------------------------------------------------------------------
__global__ void k_pool(const float* __restrict__ energy, const int* __restrict__ batch,
                       float* __restrict__ dg, int N) {
    int i = blockIdx.x * blockDim.x + threadIdx.x;
    if (i < N) atomicAdd(&dg[batch[i]], energy[i]);
}

extern "C" void kernel_launch(void* const* d_in, const int* in_sizes, int n_in,
                              void* d_out, int out_size, void* d_ws, size_t ws_size,
                              hipStream_t stream) {
    const int* atom       = (const int*)d_in[0];
    const int* bond_index = (const int*)d_in[1];
    const int* bond_attr  = (const int*)d_in[2];
    const int* batch      = (const int*)d_in[3];
    const float* Wa   = (const float*)d_in[4];
    const float* Wh   = (const float*)d_in[5];
    const float* War  = (const float*)d_in[6];
    const float* Wc   = (const float*)d_in[7];
    const float* Wch  = (const float*)d_in[8];
    const float* Wbt  = (const float*)d_in[9];
    const float* Wbai = (const float*)d_in[10];
    const float* Wsla = (const float*)d_in[11];
    const float* Wsl  = (const float*)d_in[12];
    const float* W1   = (const float*)d_in[13];
    const float* b1   = (const float*)d_in[14];
    const float* W2   = (const float*)d_in[15];
    const float* b2   = (const float*)d_in[16];
    const float* W3   = (const float*)d_in[17];

    int N = in_sizes[0] / 5;   // 50000
    int E = in_sizes[1] / 2;   // 100000
    size_t NE = (size_t)N * EMB;

    float* bufA = (float*)d_ws;          // node fp32 (ping)  | later H1hi/H1lo
    float* bufB = bufA + NE;             // node fp32 (pong)  | later Ahi/Alo
    // bf16 aliases
    ushortT* Hhi = (ushortT*)bufA;
    ushortT* Hlo = Hhi + NE;
    ushortT* Ahi = (ushortT*)bufB;
    ushortT* Alo = Ahi + NE;
    // tail scratch
    float* energy  = bufB + NE;
    int* counts    = (int*)(energy + N);
    int* offsets   = counts + N;
    int* cursor    = offsets + N;
    int* edge_list = cursor + N;
    ushortT* W1hi  = (ushortT*)(edge_list + E);
    ushortT* W1lo  = W1hi + 608 * 608;
    ushortT* W2hi  = W1lo + 608 * 608;
    ushortT* W2lo  = W2hi + 304 * 608;

    const int* bsrc = bond_index;
    const int* bdst = bond_index + E;

    // CSR build (dst -> edges)
    hipMemsetAsync(counts, 0, (size_t)N * sizeof(int), stream);
    k_hist<<<(E + 255) / 256, 256, 0, stream>>>(bdst, counts, E);
    k_scan<<<1, 1024, 0, stream>>>(counts, offsets, cursor, N);
    k_scatter<<<(E + 255) / 256, 256, 0, stream>>>(bdst, cursor, edge_list, E);

    // weight splits (small)
    k_split_w<<<(608 * 76 + 255) / 256, 256, 0, stream>>>(W1, W1hi, W1lo, 600, 608);
    k_split_w<<<(304 * 76 + 255) / 256, 256, 0, stream>>>(W2, W2hi, W2lo, 300, 304);

    // K1: node embedding -> bufA
    {
        int total = N * Q4;
        k_node_embed<<<(total + 255) / 256, 256, 0, stream>>>(
            atom, (const float4*)Wa, (const float4*)Wh, (const float4*)War,
            (const float4*)Wc, (const float4*)Wch, (float4*)bufA, N);
    }

    int mpblocks = (N * 64 + 255) / 256;
    // round 1: A -> B
    k_mp_gather<<<mpblocks, 256, 0, stream>>>(bsrc, bond_attr, atom,
        offsets, counts, edge_list,
        (const float4*)Wbt, (const float4*)Wbai, (const float4*)Wsla, (const float4*)Wsl,
        (const float4*)bufA, (float4*)bufB, N);
    // round 2: B -> A
    k_mp_gather<<<mpblocks, 256, 0, stream>>>(bsrc, bond_attr, atom,
        offsets, counts, edge_list,
        (const float4*)Wbt, (const float4*)Wbai, (const float4*)Wsla, (const float4*)Wsl,
        (const float4*)bufB, (float4*)bufA, N);

    // split relu(node) -> Ahi/Alo (overwrites bufB, which is dead)
    k_split_relu<<<(N * 75 + 255) / 256, 256, 0, stream>>>(bufA, Ahi, Alo, N);

    int Mb = (N + 63) / 64;
    // GEMM1: Ahi/Alo x W1 -> Hhi/Hlo (overwrites bufA, which is dead)
    {
        dim3 grid(Mb, 2);
        k_gemm1<<<grid, 256, 0, stream>>>(Ahi, Alo, W1hi, W1lo, b1, Hhi, Hlo, N);
    }
    // GEMM2: Hhi/Hlo x W2 (+b2, W3) -> energy
    k_gemm2<<<Mb, 256, 0, stream>>>(Hhi, Hlo, W2hi, W2lo, b2, W3, energy, N);

    // pool
    hipMemsetAsync(d_out, 0, (size_t)out_size * sizeof(float), stream);
    k_pool<<<(N + 255) / 256, 256, 0, stream>>>(energy, batch, (float*)d_out, N);
}

// Round 4
// 1051.497 us; speedup vs baseline: 3.6359x; 1.1662x over previous
//
#include <hip/hip_runtime.h>

#define EMB 600
#define Q4  150   // EMB / 4
#define KP  608   // K padded (19 * 32)

typedef unsigned short ushortT;
typedef __attribute__((ext_vector_type(8))) short short8;
typedef __attribute__((ext_vector_type(4))) float f32x4;

__device__ __forceinline__ float4 f4add(float4 a, float4 b) {
    return make_float4(a.x + b.x, a.y + b.y, a.z + b.z, a.w + b.w);
}
__device__ __forceinline__ float4 f4fma(float4 acc, float4 v, float4 e) {
    return make_float4(fmaf(v.x, e.x, acc.x), fmaf(v.y, e.y, acc.y),
                       fmaf(v.z, e.z, acc.z), fmaf(v.w, e.w, acc.w));
}
__device__ __forceinline__ ushortT bf16_rne(float x) {
    unsigned u = __float_as_uint(x);
    return (ushortT)((u + 0x7fffu + ((u >> 16) & 1u)) >> 16);
}
__device__ __forceinline__ float bf16_to_f(ushortT h) {
    return __uint_as_float(((unsigned)h) << 16);
}

// ---------------------------------------------------------------------------
// K1: node embedding = sum of 5 table lookups.
// ---------------------------------------------------------------------------
__global__ void k_node_embed(const int* __restrict__ atom,
                             const float4* __restrict__ Wa,
                             const float4* __restrict__ Wh,
                             const float4* __restrict__ War,
                             const float4* __restrict__ Wc,
                             const float4* __restrict__ Wch,
                             float4* __restrict__ out, int N) {
    int idx = blockIdx.x * blockDim.x + threadIdx.x;
    int total = N * Q4;
    if (idx >= total) return;
    int n = idx / Q4;
    int q = idx - n * Q4;
    const int* a = atom + n * 5;
    float4 r = Wa[a[0] * Q4 + q];
    r = f4add(r, Wh [a[1] * Q4 + q]);
    r = f4add(r, War[a[2] * Q4 + q]);
    r = f4add(r, Wc [a[3] * Q4 + q]);
    r = f4add(r, Wch[a[4] * Q4 + q]);
    out[idx] = r;
}

// ---------------------------------------------------------------------------
// CSR build: histogram -> scan -> scatter
// ---------------------------------------------------------------------------
__global__ void k_hist(const int* __restrict__ bdst, int* __restrict__ counts, int E) {
    int i = blockIdx.x * blockDim.x + threadIdx.x;
    if (i < E) atomicAdd(&counts[bdst[i]], 1);
}

__global__ __launch_bounds__(1024) void k_scan(const int* __restrict__ counts,
                                               int* __restrict__ offsets,
                                               int* __restrict__ cursor, int N) {
    __shared__ int sums[1024];
    int t = threadIdx.x;
    int chunk = (N + 1023) / 1024;
    int begin = t * chunk;
    int end = begin + chunk; if (end > N) end = N;
    int s = 0;
    for (int i = begin; i < end; i++) s += counts[i];
    sums[t] = s;
    __syncthreads();
    for (int off = 1; off < 1024; off <<= 1) {
        int v = (t >= off) ? sums[t - off] : 0;
        __syncthreads();
        sums[t] += v;
        __syncthreads();
    }
    int run = (t == 0) ? 0 : sums[t - 1];
    for (int i = begin; i < end; i++) {
        offsets[i] = run;
        cursor[i]  = run;
        run += counts[i];
    }
}

__global__ void k_scatter(const int* __restrict__ bdst, int* __restrict__ cursor,
                          int* __restrict__ edge_list, int E) {
    int i = blockIdx.x * blockDim.x + threadIdx.x;
    if (i < E) {
        int pos = atomicAdd(&cursor[bdst[i]], 1);
        edge_list[pos] = i;
    }
}

// ---------------------------------------------------------------------------
// K2: message-passing round, CSR gather form. One wave per dest node.
// ---------------------------------------------------------------------------
__global__ __launch_bounds__(256) void k_mp_gather(
        const int* __restrict__ bsrc, const int* __restrict__ battr,
        const int* __restrict__ atom,
        const int* __restrict__ offsets, const int* __restrict__ counts,
        const int* __restrict__ edge_list,
        const float4* __restrict__ Wbt, const float4* __restrict__ Wbai,
        const float4* __restrict__ Wsla, const float4* __restrict__ Wsl,
        const float4* __restrict__ in, float4* __restrict__ out, int N) {
    int wid  = (int)((blockIdx.x * blockDim.x + threadIdx.x) >> 6);
    int lane = threadIdx.x & 63;
    if (wid >= N) return;
    int d = wid;
    int q0 = lane, q1 = lane + 64, q2 = lane + 128;
    bool has2 = (q2 < Q4);

    const float4* slA = Wsla + atom[d * 5] * Q4;
    const float4* inr = in + (size_t)d * Q4;
    float4 acc0 = make_float4(0, 0, 0, 0), acc1 = acc0, acc2 = acc0;
    acc0 = f4fma(acc0, inr[q0], f4add(slA[q0], Wsl[q0]));
    acc1 = f4fma(acc1, inr[q1], f4add(slA[q1], Wsl[q1]));
    if (has2) acc2 = f4fma(acc2, inr[q2], f4add(slA[q2], Wsl[q2]));

    int start = offsets[d], cnt = counts[d];
    for (int k = 0; k < cnt; k++) {
        int eid = edge_list[start + k];
        int s   = bsrc[eid];
        int t0  = battr[eid * 2 + 0];
        int t1  = battr[eid * 2 + 1];
        const float4* e0 = Wbt  + t0 * Q4;
        const float4* e1 = Wbai + t1 * Q4;
        const float4* sr = in + (size_t)s * Q4;
        acc0 = f4fma(acc0, sr[q0], f4add(e0[q0], e1[q0]));
        acc1 = f4fma(acc1, sr[q1], f4add(e0[q1], e1[q1]));
        if (has2) acc2 = f4fma(acc2, sr[q2], f4add(e0[q2], e1[q2]));
    }
    float4* orow = out + (size_t)d * Q4;
    orow[q0] = acc0;
    orow[q1] = acc1;
    if (has2) orow[q2] = acc2;
}

// ---------------------------------------------------------------------------
// Split: relu(node fp32 [N][600]) -> Ahi/Alo [N][608] bf16 (zero-padded tail)
// ---------------------------------------------------------------------------
__global__ void k_split_relu(const float* __restrict__ src,
                             ushortT* __restrict__ hi, ushortT* __restrict__ lo,
                             int N) {
    int idx = blockIdx.x * blockDim.x + threadIdx.x;
    int total = N * 76;                  // 76 ushort8 units per padded row
    if (idx >= total) return;
    int row = idx / 76;
    int u   = idx - row * 76;
    ushortT h[8], l[8];
    if (u < 75) {
        const float* p = src + (size_t)row * 600 + u * 8;
#pragma unroll
        for (int j = 0; j < 8; j++) {
            float x = fmaxf(p[j], 0.f);
            ushortT hh = bf16_rne(x);
            h[j] = hh;
            l[j] = bf16_rne(x - bf16_to_f(hh));
        }
    } else {
#pragma unroll
        for (int j = 0; j < 8; j++) { h[j] = 0; l[j] = 0; }
    }
    *(short8*)(hi + (size_t)row * KP + u * 8) = *(short8*)h;
    *(short8*)(lo + (size_t)row * KP + u * 8) = *(short8*)l;
}

// weights: src[rows_in][600] -> hi/lo [rows_out][608], zero-padded
__global__ void k_split_w(const float* __restrict__ src,
                          ushortT* __restrict__ hi, ushortT* __restrict__ lo,
                          int rows_in, int rows_out) {
    int idx = blockIdx.x * blockDim.x + threadIdx.x;
    int total = rows_out * 76;
    if (idx >= total) return;
    int row = idx / 76;
    int u   = idx - row * 76;
    ushortT h[8], l[8];
    if (row < rows_in && u < 75) {
        const float* p = src + (size_t)row * 600 + u * 8;
#pragma unroll
        for (int j = 0; j < 8; j++) {
            float x = p[j];
            ushortT hh = bf16_rne(x);
            h[j] = hh;
            l[j] = bf16_rne(x - bf16_to_f(hh));
        }
    } else {
#pragma unroll
        for (int j = 0; j < 8; j++) { h[j] = 0; l[j] = 0; }
    }
    *(short8*)(hi + (size_t)row * KP + u * 8) = *(short8*)h;
    *(short8*)(lo + (size_t)row * KP + u * 8) = *(short8*)l;
}

// ---------------------------------------------------------------------------
// MFMA GEMM core (bf16x3): 128x128 tile, BK=32, 256 threads = 4 waves (2x2),
// each wave 64x64 = 4x4 fragments of 16x16x32. A and B both staged in LDS
// (pitch 36 ushorts, ~conflict-free). Reg-prefetch of next K-chunk hides
// global latency under the MFMA burst. K = 608 exactly (19 chunks).
// ---------------------------------------------------------------------------
#define LP 36   // LDS pitch in ushorts

__device__ __forceinline__ void gemm_core_v2(
        const ushortT* __restrict__ Ahi, const ushortT* __restrict__ Alo,
        const ushortT* __restrict__ Whi, const ushortT* __restrict__ Wlo,
        int row0, int col0, int N, f32x4 acc[4][4], ushortT* lds) {
    ushortT* sAhi = lds;
    ushortT* sAlo = sAhi + 128 * LP;
    ushortT* sBhi = sAlo + 128 * LP;
    ushortT* sBlo = sBhi + 128 * LP;

    const int t = threadIdx.x;
    const int w = t >> 6;
    const int l = t & 63;
    const int wr = w >> 1, wc = w & 1;
    const int srow = t >> 2;   // 0..63
    const int slot = t & 3;    // k8 group
    const int fr = l & 15;
    const int kk = (l >> 4) * 8;
    const short8 z8 = {0, 0, 0, 0, 0, 0, 0, 0};

    short8 ra_h[2], ra_l[2], rb_h[2], rb_l[2];

#define LOADK(kc)                                                           \
    {                                                                       \
        int kbase = (kc) * 32 + slot * 8;                                   \
        _Pragma("unroll")                                                   \
        for (int r = 0; r < 2; r++) {                                       \
            int ar = row0 + r * 64 + srow;                                  \
            bool av = ar < N;                                               \
            ra_h[r] = av ? *(const short8*)(Ahi + (size_t)ar * KP + kbase) : z8; \
            ra_l[r] = av ? *(const short8*)(Alo + (size_t)ar * KP + kbase) : z8; \
            int br = col0 + r * 64 + srow;                                  \
            rb_h[r] = *(const short8*)(Whi + (size_t)br * KP + kbase);      \
            rb_l[r] = *(const short8*)(Wlo + (size_t)br * KP + kbase);      \
        }                                                                   \
    }

    LOADK(0);
    for (int kc = 0; kc < 19; kc++) {
#pragma unroll
        for (int r = 0; r < 2; r++) {
            int off = (r * 64 + srow) * LP + slot * 8;
            *(short8*)&sAhi[off] = ra_h[r];
            *(short8*)&sAlo[off] = ra_l[r];
            *(short8*)&sBhi[off] = rb_h[r];
            *(short8*)&sBlo[off] = rb_l[r];
        }
        __syncthreads();
        if (kc < 18) LOADK(kc + 1);

        short8 bh[4], bl[4];
#pragma unroll
        for (int j = 0; j < 4; j++) {
            int co = (wc * 64 + j * 16 + fr) * LP + kk;
            bh[j] = *(short8*)&sBhi[co];
            bl[j] = *(short8*)&sBlo[co];
        }
#pragma unroll
        for (int i = 0; i < 4; i++) {
            int ro = (wr * 64 + i * 16 + fr) * LP + kk;
            short8 ah = *(short8*)&sAhi[ro];
            short8 al = *(short8*)&sAlo[ro];
#pragma unroll
            for (int j = 0; j < 4; j++) {
                acc[i][j] = __builtin_amdgcn_mfma_f32_16x16x32_bf16(ah, bh[j], acc[i][j], 0, 0, 0);
                acc[i][j] = __builtin_amdgcn_mfma_f32_16x16x32_bf16(ah, bl[j], acc[i][j], 0, 0, 0);
                acc[i][j] = __builtin_amdgcn_mfma_f32_16x16x32_bf16(al, bh[j], acc[i][j], 0, 0, 0);
            }
        }
        __syncthreads();
    }
#undef LOADK
}

// GEMM1: H = relu(A @ W1^T + b1) -> Hhi/Hlo [N][608].  grid (Mb, 5)
__global__ __launch_bounds__(256, 3) void k_gemm1(
        const ushortT* __restrict__ Ahi, const ushortT* __restrict__ Alo,
        const ushortT* __restrict__ Whi, const ushortT* __restrict__ Wlo,
        const float* __restrict__ b1,
        ushortT* __restrict__ Hhi, ushortT* __restrict__ Hlo, int N) {
    __shared__ ushortT lds[4 * 128 * LP];
    int row0 = blockIdx.x * 128;
    int col0 = blockIdx.y * 128;
    f32x4 acc[4][4];
#pragma unroll
    for (int i = 0; i < 4; i++)
#pragma unroll
        for (int j = 0; j < 4; j++) acc[i][j] = f32x4{0.f, 0.f, 0.f, 0.f};
    gemm_core_v2(Ahi, Alo, Whi, Wlo, row0, col0, N, acc, lds);

    int t = threadIdx.x, w = t >> 6, l = t & 63;
    int wr = w >> 1, wc = w & 1, fr = l & 15, fq = l >> 4;
#pragma unroll
    for (int i = 0; i < 4; i++) {
        int row_b = row0 + wr * 64 + i * 16 + fq * 4;
#pragma unroll
        for (int j = 0; j < 4; j++) {
            int col = col0 + wc * 64 + j * 16 + fr;
            if (col < 600) {
                float bias = b1[col];
#pragma unroll
                for (int r = 0; r < 4; r++) {
                    int row = row_b + r;
                    if (row < N) {
                        float x = fmaxf(acc[i][j][r] + bias, 0.f);
                        ushortT hh = bf16_rne(x);
                        Hhi[(size_t)row * KP + col] = hh;
                        Hlo[(size_t)row * KP + col] = bf16_rne(x - bf16_to_f(hh));
                    }
                }
            } else if (col < KP) {
#pragma unroll
                for (int r = 0; r < 4; r++) {
                    int row = row_b + r;
                    if (row < N) {
                        Hhi[(size_t)row * KP + col] = 0;
                        Hlo[(size_t)row * KP + col] = 0;
                    }
                }
            }
        }
    }
}

// GEMM2: energy += sum_col relu(H @ W2^T + b2) * W3.  grid (Mb, 3)
__global__ __launch_bounds__(256, 3) void k_gemm2(
        const ushortT* __restrict__ Ahi, const ushortT* __restrict__ Alo,
        const ushortT* __restrict__ Whi, const ushortT* __restrict__ Wlo,
        const float* __restrict__ b2, const float* __restrict__ W3,
        float* __restrict__ energy, int N) {
    __shared__ ushortT lds[4 * 128 * LP];
    __shared__ float sE[128];
    int row0 = blockIdx.x * 128;
    int col0 = blockIdx.y * 128;
    f32x4 acc[4][4];
#pragma unroll
    for (int i = 0; i < 4; i++)
#pragma unroll
        for (int j = 0; j < 4; j++) acc[i][j] = f32x4{0.f, 0.f, 0.f, 0.f};
    gemm_core_v2(Ahi, Alo, Whi, Wlo, row0, col0, N, acc, lds);

    int t = threadIdx.x, w = t >> 6, l = t & 63;
    int wr = w >> 1, wc = w & 1, fr = l & 15, fq = l >> 4;
    if (t < 128) sE[t] = 0.f;
    __syncthreads();
#pragma unroll
    for (int i = 0; i < 4; i++) {
        float p[4] = {0.f, 0.f, 0.f, 0.f};
#pragma unroll
        for (int j = 0; j < 4; j++) {
            int col = col0 + wc * 64 + j * 16 + fr;
            if (col < 300) {
                float bias = b2[col];
                float wv   = W3[col];
#pragma unroll
                for (int r = 0; r < 4; r++)
                    p[r] += fmaxf(acc[i][j][r] + bias, 0.f) * wv;
            }
        }
#pragma unroll
        for (int r = 0; r < 4; r++) {
            float v = p[r];
            v += __shfl_xor(v, 1, 64);
            v += __shfl_xor(v, 2, 64);
            v += __shfl_xor(v, 4, 64);
            v += __shfl_xor(v, 8, 64);
            p[r] = v;
        }
        if (fr == 0) {
#pragma unroll
            for (int r = 0; r < 4; r++)
                atomicAdd(&sE[wr * 64 + i * 16 + fq * 4 + r], p[r]);
        }
    }
    __syncthreads();
    if (t < 128) {
        int row = row0 + t;
        if (row < N) atomicAdd(&energy[row], sE[t]);
    }
}

// ---------------------------------------------------------------------------
// K5: per-graph pool
// ---------------------------------------------------------------------------
__global__ void k_pool(const float* __restrict__ energy, const int* __restrict__ batch,
                       float* __restrict__ dg, int N) {
    int i = blockIdx.x * blockDim.x + threadIdx.x;
    if (i < N) atomicAdd(&dg[batch[i]], energy[i]);
}

extern "C" void kernel_launch(void* const* d_in, const int* in_sizes, int n_in,
                              void* d_out, int out_size, void* d_ws, size_t ws_size,
                              hipStream_t stream) {
    const int* atom       = (const int*)d_in[0];
    const int* bond_index = (const int*)d_in[1];
    const int* bond_attr  = (const int*)d_in[2];
    const int* batch      = (const int*)d_in[3];
    const float* Wa   = (const float*)d_in[4];
    const float* Wh   = (const float*)d_in[5];
    const float* War  = (const float*)d_in[6];
    const float* Wc   = (const float*)d_in[7];
    const float* Wch  = (const float*)d_in[8];
    const float* Wbt  = (const float*)d_in[9];
    const float* Wbai = (const float*)d_in[10];
    const float* Wsla = (const float*)d_in[11];
    const float* Wsl  = (const float*)d_in[12];
    const float* W1   = (const float*)d_in[13];
    const float* b1   = (const float*)d_in[14];
    const float* W2   = (const float*)d_in[15];
    const float* b2   = (const float*)d_in[16];
    const float* W3   = (const float*)d_in[17];

    int N = in_sizes[0] / 5;   // 50000
    int E = in_sizes[1] / 2;   // 100000

    size_t regionBytes = (size_t)N * KP * 4;   // holds fp32[N][600] or 2x bf16[N][608]
    char* base = (char*)d_ws;
    float* nodeA = (float*)base;                       // region0
    float* nodeB = (float*)(base + regionBytes);       // region1
    // bf16 aliases: A over region1 (nodeB dead after MP), H over region0
    ushortT* Ahi = (ushortT*)nodeB;
    ushortT* Alo = Ahi + (size_t)N * KP;
    ushortT* Hhi = (ushortT*)nodeA;
    ushortT* Hlo = Hhi + (size_t)N * KP;
    // tail scratch
    char* tail = base + 2 * regionBytes;
    float* energy  = (float*)tail;
    int* counts    = (int*)(energy + N);
    int* offsets   = counts + N;
    int* cursor    = offsets + N;
    int* edge_list = cursor + N;
    ushortT* W1hi  = (ushortT*)(edge_list + E);
    ushortT* W1lo  = W1hi + (size_t)640 * KP;
    ushortT* W2hi  = W1lo + (size_t)640 * KP;
    ushortT* W2lo  = W2hi + (size_t)384 * KP;

    const int* bsrc = bond_index;
    const int* bdst = bond_index + E;

    // CSR build (dst -> edges)
    hipMemsetAsync(counts, 0, (size_t)N * sizeof(int), stream);
    k_hist<<<(E + 255) / 256, 256, 0, stream>>>(bdst, counts, E);
    k_scan<<<1, 1024, 0, stream>>>(counts, offsets, cursor, N);
    k_scatter<<<(E + 255) / 256, 256, 0, stream>>>(bdst, cursor, edge_list, E);

    // weight splits
    k_split_w<<<(640 * 76 + 255) / 256, 256, 0, stream>>>(W1, W1hi, W1lo, 600, 640);
    k_split_w<<<(384 * 76 + 255) / 256, 256, 0, stream>>>(W2, W2hi, W2lo, 300, 384);

    // K1: node embedding -> nodeA
    {
        int total = N * Q4;
        k_node_embed<<<(total + 255) / 256, 256, 0, stream>>>(
            atom, (const float4*)Wa, (const float4*)Wh, (const float4*)War,
            (const float4*)Wc, (const float4*)Wch, (float4*)nodeA, N);
    }

    int mpblocks = (N * 64 + 255) / 256;
    // round 1: A -> B
    k_mp_gather<<<mpblocks, 256, 0, stream>>>(bsrc, bond_attr, atom,
        offsets, counts, edge_list,
        (const float4*)Wbt, (const float4*)Wbai, (const float4*)Wsla, (const float4*)Wsl,
        (const float4*)nodeA, (float4*)nodeB, N);
    // round 2: B -> A
    k_mp_gather<<<mpblocks, 256, 0, stream>>>(bsrc, bond_attr, atom,
        offsets, counts, edge_list,
        (const float4*)Wbt, (const float4*)Wbai, (const float4*)Wsla, (const float4*)Wsl,
        (const float4*)nodeB, (float4*)nodeA, N);

    // split relu(nodeA) -> Ahi/Alo (over region1; nodeB dead)
    k_split_relu<<<(N * 76 + 255) / 256, 256, 0, stream>>>(nodeA, Ahi, Alo, N);

    int Mb = (N + 127) / 128;
    // GEMM1: Ahi/Alo x W1 -> Hhi/Hlo (over region0; nodeA fp32 dead)
    {
        dim3 grid(Mb, 5);
        k_gemm1<<<grid, 256, 0, stream>>>(Ahi, Alo, W1hi, W1lo, b1, Hhi, Hlo, N);
    }
    // GEMM2: Hhi/Hlo x W2 (+b2, W3) -> energy (atomic accumulate)
    hipMemsetAsync(energy, 0, (size_t)N * sizeof(float), stream);
    {
        dim3 grid(Mb, 3);
        k_gemm2<<<grid, 256, 0, stream>>>(Hhi, Hlo, W2hi, W2lo, b2, W3, energy, N);
    }

    // pool
    hipMemsetAsync(d_out, 0, (size_t)out_size * sizeof(float), stream);
    k_pool<<<(N + 255) / 256, 256, 0, stream>>>(energy, batch, (float*)d_out, N);
}

// Round 5
// 651.453 us; speedup vs baseline: 5.8686x; 1.6141x over previous
//
#include <hip/hip_runtime.h>

#define EMB 600
#define Q4  150   // EMB / 4
#define KP  608   // K padded (19 * 32)

typedef unsigned short ushortT;
typedef __attribute__((ext_vector_type(8))) short short8;
typedef __attribute__((ext_vector_type(4))) float f32x4;

__device__ __forceinline__ float4 f4add(float4 a, float4 b) {
    return make_float4(a.x + b.x, a.y + b.y, a.z + b.z, a.w + b.w);
}
__device__ __forceinline__ float4 f4fma(float4 acc, float4 v, float4 e) {
    return make_float4(fmaf(v.x, e.x, acc.x), fmaf(v.y, e.y, acc.y),
                       fmaf(v.z, e.z, acc.z), fmaf(v.w, e.w, acc.w));
}
__device__ __forceinline__ ushortT bf16_rne(float x) {
    unsigned u = __float_as_uint(x);
    return (ushortT)((u + 0x7fffu + ((u >> 16) & 1u)) >> 16);
}
__device__ __forceinline__ float bf16_to_f(ushortT h) {
    return __uint_as_float(((unsigned)h) << 16);
}

// async global -> LDS, 16B per lane. Global src per-lane; LDS base wave-uniform.
#define GLDS(g, l)                                                            \
    __builtin_amdgcn_global_load_lds(                                         \
        (const __attribute__((address_space(1))) void*)(g),                   \
        (__attribute__((address_space(3))) void*)(l), 16, 0, 0)

// ---------------------------------------------------------------------------
// K1: node embedding = sum of 5 table lookups.
// ---------------------------------------------------------------------------
__global__ void k_node_embed(const int* __restrict__ atom,
                             const float4* __restrict__ Wa,
                             const float4* __restrict__ Wh,
                             const float4* __restrict__ War,
                             const float4* __restrict__ Wc,
                             const float4* __restrict__ Wch,
                             float4* __restrict__ out, int N) {
    int idx = blockIdx.x * blockDim.x + threadIdx.x;
    int total = N * Q4;
    if (idx >= total) return;
    int n = idx / Q4;
    int q = idx - n * Q4;
    const int* a = atom + n * 5;
    float4 r = Wa[a[0] * Q4 + q];
    r = f4add(r, Wh [a[1] * Q4 + q]);
    r = f4add(r, War[a[2] * Q4 + q]);
    r = f4add(r, Wc [a[3] * Q4 + q]);
    r = f4add(r, Wch[a[4] * Q4 + q]);
    out[idx] = r;
}

// ---------------------------------------------------------------------------
// CSR build: histogram -> scan -> scatter
// ---------------------------------------------------------------------------
__global__ void k_hist(const int* __restrict__ bdst, int* __restrict__ counts, int E) {
    int i = blockIdx.x * blockDim.x + threadIdx.x;
    if (i < E) atomicAdd(&counts[bdst[i]], 1);
}

__global__ __launch_bounds__(1024) void k_scan(const int* __restrict__ counts,
                                               int* __restrict__ offsets,
                                               int* __restrict__ cursor, int N) {
    __shared__ int sums[1024];
    int t = threadIdx.x;
    int chunk = (N + 1023) / 1024;
    int begin = t * chunk;
    int end = begin + chunk; if (end > N) end = N;
    int s = 0;
    for (int i = begin; i < end; i++) s += counts[i];
    sums[t] = s;
    __syncthreads();
    for (int off = 1; off < 1024; off <<= 1) {
        int v = (t >= off) ? sums[t - off] : 0;
        __syncthreads();
        sums[t] += v;
        __syncthreads();
    }
    int run = (t == 0) ? 0 : sums[t - 1];
    for (int i = begin; i < end; i++) {
        offsets[i] = run;
        cursor[i]  = run;
        run += counts[i];
    }
}

__global__ void k_scatter(const int* __restrict__ bdst, int* __restrict__ cursor,
                          int* __restrict__ edge_list, int E) {
    int i = blockIdx.x * blockDim.x + threadIdx.x;
    if (i < E) {
        int pos = atomicAdd(&cursor[bdst[i]], 1);
        edge_list[pos] = i;
    }
}

// ---------------------------------------------------------------------------
// K2: message-passing round, CSR gather form. One wave per dest node.
// ---------------------------------------------------------------------------
__global__ __launch_bounds__(256) void k_mp_gather(
        const int* __restrict__ bsrc, const int* __restrict__ battr,
        const int* __restrict__ atom,
        const int* __restrict__ offsets, const int* __restrict__ counts,
        const int* __restrict__ edge_list,
        const float4* __restrict__ Wbt, const float4* __restrict__ Wbai,
        const float4* __restrict__ Wsla, const float4* __restrict__ Wsl,
        const float4* __restrict__ in, float4* __restrict__ out, int N) {
    int wid  = (int)((blockIdx.x * blockDim.x + threadIdx.x) >> 6);
    int lane = threadIdx.x & 63;
    if (wid >= N) return;
    int d = wid;
    int q0 = lane, q1 = lane + 64, q2 = lane + 128;
    bool has2 = (q2 < Q4);

    const float4* slA = Wsla + atom[d * 5] * Q4;
    const float4* inr = in + (size_t)d * Q4;
    float4 acc0 = make_float4(0, 0, 0, 0), acc1 = acc0, acc2 = acc0;
    acc0 = f4fma(acc0, inr[q0], f4add(slA[q0], Wsl[q0]));
    acc1 = f4fma(acc1, inr[q1], f4add(slA[q1], Wsl[q1]));
    if (has2) acc2 = f4fma(acc2, inr[q2], f4add(slA[q2], Wsl[q2]));

    int start = offsets[d], cnt = counts[d];
    for (int k = 0; k < cnt; k++) {
        int eid = edge_list[start + k];
        int s   = bsrc[eid];
        int t0  = battr[eid * 2 + 0];
        int t1  = battr[eid * 2 + 1];
        const float4* e0 = Wbt  + t0 * Q4;
        const float4* e1 = Wbai + t1 * Q4;
        const float4* sr = in + (size_t)s * Q4;
        acc0 = f4fma(acc0, sr[q0], f4add(e0[q0], e1[q0]));
        acc1 = f4fma(acc1, sr[q1], f4add(e0[q1], e1[q1]));
        if (has2) acc2 = f4fma(acc2, sr[q2], f4add(e0[q2], e1[q2]));
    }
    float4* orow = out + (size_t)d * Q4;
    orow[q0] = acc0;
    orow[q1] = acc1;
    if (has2) orow[q2] = acc2;
}

// ---------------------------------------------------------------------------
// Split: relu(node fp32 [N][600]) -> Ahi/Alo [N][608] bf16 (zero-padded tail)
// ---------------------------------------------------------------------------
__global__ void k_split_relu(const float* __restrict__ src,
                             ushortT* __restrict__ hi, ushortT* __restrict__ lo,
                             int N) {
    int idx = blockIdx.x * blockDim.x + threadIdx.x;
    int total = N * 76;
    if (idx >= total) return;
    int row = idx / 76;
    int u   = idx - row * 76;
    ushortT h[8], l[8];
    if (u < 75) {
        const float* p = src + (size_t)row * 600 + u * 8;
#pragma unroll
        for (int j = 0; j < 8; j++) {
            float x = fmaxf(p[j], 0.f);
            ushortT hh = bf16_rne(x);
            h[j] = hh;
            l[j] = bf16_rne(x - bf16_to_f(hh));
        }
    } else {
#pragma unroll
        for (int j = 0; j < 8; j++) { h[j] = 0; l[j] = 0; }
    }
    *(short8*)(hi + (size_t)row * KP + u * 8) = *(short8*)h;
    *(short8*)(lo + (size_t)row * KP + u * 8) = *(short8*)l;
}

// weights: src[rows_in][600] -> hi/lo [rows_out][608], zero-padded
__global__ void k_split_w(const float* __restrict__ src,
                          ushortT* __restrict__ hi, ushortT* __restrict__ lo,
                          int rows_in, int rows_out) {
    int idx = blockIdx.x * blockDim.x + threadIdx.x;
    int total = rows_out * 76;
    if (idx >= total) return;
    int row = idx / 76;
    int u   = idx - row * 76;
    ushortT h[8], l[8];
    if (row < rows_in && u < 75) {
        const float* p = src + (size_t)row * 600 + u * 8;
#pragma unroll
        for (int j = 0; j < 8; j++) {
            float x = p[j];
            ushortT hh = bf16_rne(x);
            h[j] = hh;
            l[j] = bf16_rne(x - bf16_to_f(hh));
        }
    } else {
#pragma unroll
        for (int j = 0; j < 8; j++) { h[j] = 0; l[j] = 0; }
    }
    *(short8*)(hi + (size_t)row * KP + u * 8) = *(short8*)h;
    *(short8*)(lo + (size_t)row * KP + u * 8) = *(short8*)l;
}

// ---------------------------------------------------------------------------
// MFMA GEMM core v3 (bf16x3): 128x128 tile, BK=32, 256 threads = 4 waves.
// Staging via global_load_lds (16B/lane) into fragment-order LDS: chunk rb
// (16 rows x 32 k) occupies 1024B with lane l holding (row=l&15, k8=l>>4).
// All ds_read_b128 are lane-linear -> conflict-free. Double-buffered 2-phase:
// issue STAGE(kc+1) before compute(kc); one __syncthreads per K-step.
// LDS layout: sbuf[buf][arr][512] short8, arr = {Ahi, Alo, Bhi, Blo}. 64 KB.
// A rows / W rows must be padded: A to 128-multiple rows, W to col-tile mult.
// ---------------------------------------------------------------------------
__device__ __forceinline__ void gemm_core_v3(
        const ushortT* __restrict__ Ahi, const ushortT* __restrict__ Alo,
        const ushortT* __restrict__ Whi, const ushortT* __restrict__ Wlo,
        int row0, int col0, f32x4 acc[4][4], short8* sbuf) {
    const int t = threadIdx.x;
    const int w = t >> 6, l = t & 63;
    const int wr = w >> 1, wc = w & 1;
    const int fr  = l & 15;       // row/col within fragment
    const int ks_ = l >> 4;       // k8 slot 0..3

#define STAGE(nb, kc)                                                          \
    {                                                                          \
        int k0 = (kc) * 32 + ks_ * 8;                                          \
        _Pragma("unroll")                                                      \
        for (int r = 0; r < 2; r++) {                                          \
            int rb = 2 * w + r;                                                \
            const ushortT* ga_h = Ahi + (size_t)(row0 + rb * 16 + fr) * KP + k0; \
            const ushortT* ga_l = Alo + (size_t)(row0 + rb * 16 + fr) * KP + k0; \
            const ushortT* gb_h = Whi + (size_t)(col0 + rb * 16 + fr) * KP + k0; \
            const ushortT* gb_l = Wlo + (size_t)(col0 + rb * 16 + fr) * KP + k0; \
            GLDS(ga_h, &sbuf[(nb) * 2048 + 0 * 512 + rb * 64]);                \
            GLDS(ga_l, &sbuf[(nb) * 2048 + 1 * 512 + rb * 64]);                \
            GLDS(gb_h, &sbuf[(nb) * 2048 + 2 * 512 + rb * 64]);                \
            GLDS(gb_l, &sbuf[(nb) * 2048 + 3 * 512 + rb * 64]);                \
        }                                                                      \
    }

    STAGE(0, 0);
    __syncthreads();
    for (int kc = 0; kc < 19; kc++) {
        int cur = kc & 1;
        if (kc < 18) STAGE(cur ^ 1, kc + 1);

        const short8* Lb = sbuf + cur * 2048;
        short8 bh[4], bl[4];
#pragma unroll
        for (int j = 0; j < 4; j++) {
            bh[j] = Lb[2 * 512 + (wc * 4 + j) * 64 + l];
            bl[j] = Lb[3 * 512 + (wc * 4 + j) * 64 + l];
        }
#pragma unroll
        for (int i = 0; i < 4; i++) {
            short8 ah = Lb[0 * 512 + (wr * 4 + i) * 64 + l];
            short8 al = Lb[1 * 512 + (wr * 4 + i) * 64 + l];
#pragma unroll
            for (int j = 0; j < 4; j++) {
                acc[i][j] = __builtin_amdgcn_mfma_f32_16x16x32_bf16(ah, bh[j], acc[i][j], 0, 0, 0);
                acc[i][j] = __builtin_amdgcn_mfma_f32_16x16x32_bf16(ah, bl[j], acc[i][j], 0, 0, 0);
                acc[i][j] = __builtin_amdgcn_mfma_f32_16x16x32_bf16(al, bh[j], acc[i][j], 0, 0, 0);
            }
        }
        __syncthreads();   // drains vmcnt (staged loads) + lgkm, then barrier
    }
#undef STAGE
}

// GEMM1: H = relu(A @ W1^T + b1) -> Hhi/Hlo [Npad][608].  grid (Mb, 5)
__global__ __launch_bounds__(256) void k_gemm1(
        const ushortT* __restrict__ Ahi, const ushortT* __restrict__ Alo,
        const ushortT* __restrict__ Whi, const ushortT* __restrict__ Wlo,
        const float* __restrict__ b1,
        ushortT* __restrict__ Hhi, ushortT* __restrict__ Hlo, int N) {
    __shared__ short8 sbuf[4096];   // 64 KB
    int row0 = blockIdx.x * 128;
    int col0 = blockIdx.y * 128;
    f32x4 acc[4][4];
#pragma unroll
    for (int i = 0; i < 4; i++)
#pragma unroll
        for (int j = 0; j < 4; j++) acc[i][j] = f32x4{0.f, 0.f, 0.f, 0.f};
    gemm_core_v3(Ahi, Alo, Whi, Wlo, row0, col0, acc, sbuf);

    int t = threadIdx.x, w = t >> 6, l = t & 63;
    int wr = w >> 1, wc = w & 1, fr = l & 15, fq = l >> 4;
#pragma unroll
    for (int i = 0; i < 4; i++) {
        int row_b = row0 + wr * 64 + i * 16 + fq * 4;
#pragma unroll
        for (int j = 0; j < 4; j++) {
            int col = col0 + wc * 64 + j * 16 + fr;
            if (col < 600) {
                float bias = b1[col];
#pragma unroll
                for (int r = 0; r < 4; r++) {
                    int row = row_b + r;
                    if (row < N) {
                        float x = fmaxf(acc[i][j][r] + bias, 0.f);
                        ushortT hh = bf16_rne(x);
                        Hhi[(size_t)row * KP + col] = hh;
                        Hlo[(size_t)row * KP + col] = bf16_rne(x - bf16_to_f(hh));
                    }
                }
            } else if (col < KP) {
#pragma unroll
                for (int r = 0; r < 4; r++) {
                    int row = row_b + r;
                    if (row < N) {
                        Hhi[(size_t)row * KP + col] = 0;
                        Hlo[(size_t)row * KP + col] = 0;
                    }
                }
            }
        }
    }
}

// GEMM2: energy += sum_col relu(H @ W2^T + b2) * W3.  grid (Mb, 3)
__global__ __launch_bounds__(256) void k_gemm2(
        const ushortT* __restrict__ Ahi, const ushortT* __restrict__ Alo,
        const ushortT* __restrict__ Whi, const ushortT* __restrict__ Wlo,
        const float* __restrict__ b2, const float* __restrict__ W3,
        float* __restrict__ energy, int N) {
    __shared__ short8 sbuf[4096];   // 64 KB, reused below for the row-reduce
    int row0 = blockIdx.x * 128;
    int col0 = blockIdx.y * 128;
    f32x4 acc[4][4];
#pragma unroll
    for (int i = 0; i < 4; i++)
#pragma unroll
        for (int j = 0; j < 4; j++) acc[i][j] = f32x4{0.f, 0.f, 0.f, 0.f};
    gemm_core_v3(Ahi, Alo, Whi, Wlo, row0, col0, acc, sbuf);
    // core ends with __syncthreads(); LDS now reusable
    float* sE = (float*)sbuf;

    int t = threadIdx.x, w = t >> 6, l = t & 63;
    int wr = w >> 1, wc = w & 1, fr = l & 15, fq = l >> 4;
    if (t < 128) sE[t] = 0.f;
    __syncthreads();
#pragma unroll
    for (int i = 0; i < 4; i++) {
        float p[4] = {0.f, 0.f, 0.f, 0.f};
#pragma unroll
        for (int j = 0; j < 4; j++) {
            int col = col0 + wc * 64 + j * 16 + fr;
            if (col < 300) {
                float bias = b2[col];
                float wv   = W3[col];
#pragma unroll
                for (int r = 0; r < 4; r++)
                    p[r] += fmaxf(acc[i][j][r] + bias, 0.f) * wv;
            }
        }
#pragma unroll
        for (int r = 0; r < 4; r++) {
            float v = p[r];
            v += __shfl_xor(v, 1, 64);
            v += __shfl_xor(v, 2, 64);
            v += __shfl_xor(v, 4, 64);
            v += __shfl_xor(v, 8, 64);
            p[r] = v;
        }
        if (fr == 0) {
#pragma unroll
            for (int r = 0; r < 4; r++)
                atomicAdd(&sE[wr * 64 + i * 16 + fq * 4 + r], p[r]);
        }
    }
    __syncthreads();
    if (t < 128) {
        int row = row0 + t;
        if (row < N) atomicAdd(&energy[row], sE[t]);
    }
}

// ---------------------------------------------------------------------------
// K5: per-graph pool
// ---------------------------------------------------------------------------
__global__ void k_pool(const float* __restrict__ energy, const int* __restrict__ batch,
                       float* __restrict__ dg, int N) {
    int i = blockIdx.x * blockDim.x + threadIdx.x;
    if (i < N) atomicAdd(&dg[batch[i]], energy[i]);
}

extern "C" void kernel_launch(void* const* d_in, const int* in_sizes, int n_in,
                              void* d_out, int out_size, void* d_ws, size_t ws_size,
                              hipStream_t stream) {
    const int* atom       = (const int*)d_in[0];
    const int* bond_index = (const int*)d_in[1];
    const int* bond_attr  = (const int*)d_in[2];
    const int* batch      = (const int*)d_in[3];
    const float* Wa   = (const float*)d_in[4];
    const float* Wh   = (const float*)d_in[5];
    const float* War  = (const float*)d_in[6];
    const float* Wc   = (const float*)d_in[7];
    const float* Wch  = (const float*)d_in[8];
    const float* Wbt  = (const float*)d_in[9];
    const float* Wbai = (const float*)d_in[10];
    const float* Wsla = (const float*)d_in[11];
    const float* Wsl  = (const float*)d_in[12];
    const float* W1   = (const float*)d_in[13];
    const float* b1   = (const float*)d_in[14];
    const float* W2   = (const float*)d_in[15];
    const float* b2   = (const float*)d_in[16];
    const float* W3   = (const float*)d_in[17];

    int N = in_sizes[0] / 5;   // 50000
    int E = in_sizes[1] / 2;   // 100000
    int Mb = (N + 127) / 128;  // 391
    int Npad = Mb * 128;       // 50048 (A/H rows padded so GEMM tiles never fault)

    size_t regionBytes = (size_t)Npad * KP * 4;  // fp32[N][600] or 2x bf16[Npad][608]
    char* base = (char*)d_ws;
    float* nodeA = (float*)base;                       // region0
    float* nodeB = (float*)(base + regionBytes);       // region1
    // bf16 aliases: A over region1 (nodeB dead after MP), H over region0
    ushortT* Ahi = (ushortT*)nodeB;
    ushortT* Alo = Ahi + (size_t)Npad * KP;
    ushortT* Hhi = (ushortT*)nodeA;
    ushortT* Hlo = Hhi + (size_t)Npad * KP;
    // tail scratch
    char* tail = base + 2 * regionBytes;
    float* energy  = (float*)tail;
    int* counts    = (int*)(energy + N);
    int* offsets   = counts + N;
    int* cursor    = offsets + N;
    int* edge_list = cursor + N;
    ushortT* W1hi  = (ushortT*)(edge_list + E);
    ushortT* W1lo  = W1hi + (size_t)640 * KP;
    ushortT* W2hi  = W1lo + (size_t)640 * KP;
    ushortT* W2lo  = W2hi + (size_t)384 * KP;

    const int* bsrc = bond_index;
    const int* bdst = bond_index + E;

    // CSR build (dst -> edges)
    hipMemsetAsync(counts, 0, (size_t)N * sizeof(int), stream);
    k_hist<<<(E + 255) / 256, 256, 0, stream>>>(bdst, counts, E);
    k_scan<<<1, 1024, 0, stream>>>(counts, offsets, cursor, N);
    k_scatter<<<(E + 255) / 256, 256, 0, stream>>>(bdst, cursor, edge_list, E);

    // weight splits (zero-padded to 640 / 384 rows)
    k_split_w<<<(640 * 76 + 255) / 256, 256, 0, stream>>>(W1, W1hi, W1lo, 600, 640);
    k_split_w<<<(384 * 76 + 255) / 256, 256, 0, stream>>>(W2, W2hi, W2lo, 300, 384);

    // K1: node embedding -> nodeA
    {
        int total = N * Q4;
        k_node_embed<<<(total + 255) / 256, 256, 0, stream>>>(
            atom, (const float4*)Wa, (const float4*)Wh, (const float4*)War,
            (const float4*)Wc, (const float4*)Wch, (float4*)nodeA, N);
    }

    int mpblocks = (N * 64 + 255) / 256;
    // round 1: A -> B
    k_mp_gather<<<mpblocks, 256, 0, stream>>>(bsrc, bond_attr, atom,
        offsets, counts, edge_list,
        (const float4*)Wbt, (const float4*)Wbai, (const float4*)Wsla, (const float4*)Wsl,
        (const float4*)nodeA, (float4*)nodeB, N);
    // round 2: B -> A
    k_mp_gather<<<mpblocks, 256, 0, stream>>>(bsrc, bond_attr, atom,
        offsets, counts, edge_list,
        (const float4*)Wbt, (const float4*)Wbai, (const float4*)Wsla, (const float4*)Wsl,
        (const float4*)nodeB, (float4*)nodeA, N);

    // split relu(nodeA) -> Ahi/Alo (over region1; nodeB dead)
    k_split_relu<<<(N * 76 + 255) / 256, 256, 0, stream>>>(nodeA, Ahi, Alo, N);

    // GEMM1: Ahi/Alo x W1 -> Hhi/Hlo (over region0; nodeA fp32 dead)
    {
        dim3 grid(Mb, 5);
        k_gemm1<<<grid, 256, 0, stream>>>(Ahi, Alo, W1hi, W1lo, b1, Hhi, Hlo, N);
    }
    // GEMM2: Hhi/Hlo x W2 (+b2, W3) -> energy (atomic accumulate)
    hipMemsetAsync(energy, 0, (size_t)N * sizeof(float), stream);
    {
        dim3 grid(Mb, 3);
        k_gemm2<<<grid, 256, 0, stream>>>(Hhi, Hlo, W2hi, W2lo, b2, W3, energy, N);
    }

    // pool
    hipMemsetAsync(d_out, 0, (size_t)out_size * sizeof(float), stream);
    k_pool<<<(N + 255) / 256, 256, 0, stream>>>(energy, batch, (float*)d_out, N);
}

// Round 6
// 595.930 us; speedup vs baseline: 6.4153x; 1.0932x over previous
//
#include <hip/hip_runtime.h>

#define EMB 600
#define Q4  150   // EMB / 4
#define KP  608   // K padded (19 * 32)

typedef unsigned short ushortT;
typedef __attribute__((ext_vector_type(8))) short short8;
typedef __attribute__((ext_vector_type(4))) short short4v;
typedef __attribute__((ext_vector_type(4))) float f32x4;

__device__ __forceinline__ float4 f4add(float4 a, float4 b) {
    return make_float4(a.x + b.x, a.y + b.y, a.z + b.z, a.w + b.w);
}
__device__ __forceinline__ float4 f4fma(float4 acc, float4 v, float4 e) {
    return make_float4(fmaf(v.x, e.x, acc.x), fmaf(v.y, e.y, acc.y),
                       fmaf(v.z, e.z, acc.z), fmaf(v.w, e.w, acc.w));
}
__device__ __forceinline__ ushortT bf16_rne(float x) {
    unsigned u = __float_as_uint(x);
    return (ushortT)((u + 0x7fffu + ((u >> 16) & 1u)) >> 16);
}
__device__ __forceinline__ float bf16_to_f(ushortT h) {
    return __uint_as_float(((unsigned)h) << 16);
}

// async global -> LDS, 16B per lane. Global src per-lane; LDS base wave-uniform.
#define GLDS(g, l)                                                            \
    __builtin_amdgcn_global_load_lds(                                         \
        (const __attribute__((address_space(1))) void*)(g),                   \
        (__attribute__((address_space(3))) void*)(l), 16, 0, 0)

// ---------------------------------------------------------------------------
// K1: node embedding = sum of 5 table lookups.
// ---------------------------------------------------------------------------
__global__ void k_node_embed(const int* __restrict__ atom,
                             const float4* __restrict__ Wa,
                             const float4* __restrict__ Wh,
                             const float4* __restrict__ War,
                             const float4* __restrict__ Wc,
                             const float4* __restrict__ Wch,
                             float4* __restrict__ out, int N) {
    int idx = blockIdx.x * blockDim.x + threadIdx.x;
    int total = N * Q4;
    if (idx >= total) return;
    int n = idx / Q4;
    int q = idx - n * Q4;
    const int* a = atom + n * 5;
    float4 r = Wa[a[0] * Q4 + q];
    r = f4add(r, Wh [a[1] * Q4 + q]);
    r = f4add(r, War[a[2] * Q4 + q]);
    r = f4add(r, Wc [a[3] * Q4 + q]);
    r = f4add(r, Wch[a[4] * Q4 + q]);
    out[idx] = r;
}

// ---------------------------------------------------------------------------
// CSR build: histogram -> scan -> scatter
// ---------------------------------------------------------------------------
__global__ void k_hist(const int* __restrict__ bdst, int* __restrict__ counts, int E) {
    int i = blockIdx.x * blockDim.x + threadIdx.x;
    if (i < E) atomicAdd(&counts[bdst[i]], 1);
}

__global__ __launch_bounds__(1024) void k_scan(const int* __restrict__ counts,
                                               int* __restrict__ offsets,
                                               int* __restrict__ cursor, int N) {
    __shared__ int sums[1024];
    int t = threadIdx.x;
    int chunk = (N + 1023) / 1024;
    int begin = t * chunk;
    int end = begin + chunk; if (end > N) end = N;
    int s = 0;
    for (int i = begin; i < end; i++) s += counts[i];
    sums[t] = s;
    __syncthreads();
    for (int off = 1; off < 1024; off <<= 1) {
        int v = (t >= off) ? sums[t - off] : 0;
        __syncthreads();
        sums[t] += v;
        __syncthreads();
    }
    int run = (t == 0) ? 0 : sums[t - 1];
    for (int i = begin; i < end; i++) {
        offsets[i] = run;
        cursor[i]  = run;
        run += counts[i];
    }
}

__global__ void k_scatter(const int* __restrict__ bdst, int* __restrict__ cursor,
                          int* __restrict__ edge_list, int E) {
    int i = blockIdx.x * blockDim.x + threadIdx.x;
    if (i < E) {
        int pos = atomicAdd(&cursor[bdst[i]], 1);
        edge_list[pos] = i;
    }
}

// ---------------------------------------------------------------------------
// K2a: MP round 1 (fp32 out). One wave per dest node.
// ---------------------------------------------------------------------------
__global__ __launch_bounds__(256) void k_mp_gather(
        const int* __restrict__ bsrc, const int* __restrict__ battr,
        const int* __restrict__ atom,
        const int* __restrict__ offsets, const int* __restrict__ counts,
        const int* __restrict__ edge_list,
        const float4* __restrict__ Wbt, const float4* __restrict__ Wbai,
        const float4* __restrict__ Wsla, const float4* __restrict__ Wsl,
        const float4* __restrict__ in, float4* __restrict__ out, int N) {
    int wid  = (int)((blockIdx.x * blockDim.x + threadIdx.x) >> 6);
    int lane = threadIdx.x & 63;
    if (wid >= N) return;
    int d = wid;
    int q0 = lane, q1 = lane + 64, q2 = lane + 128;
    bool has2 = (q2 < Q4);

    const float4* slA = Wsla + atom[d * 5] * Q4;
    const float4* inr = in + (size_t)d * Q4;
    float4 acc0 = make_float4(0, 0, 0, 0), acc1 = acc0, acc2 = acc0;
    acc0 = f4fma(acc0, inr[q0], f4add(slA[q0], Wsl[q0]));
    acc1 = f4fma(acc1, inr[q1], f4add(slA[q1], Wsl[q1]));
    if (has2) acc2 = f4fma(acc2, inr[q2], f4add(slA[q2], Wsl[q2]));

    int start = offsets[d], cnt = counts[d];
    for (int k = 0; k < cnt; k++) {
        int eid = edge_list[start + k];
        int s   = bsrc[eid];
        int t0  = battr[eid * 2 + 0];
        int t1  = battr[eid * 2 + 1];
        const float4* e0 = Wbt  + t0 * Q4;
        const float4* e1 = Wbai + t1 * Q4;
        const float4* sr = in + (size_t)s * Q4;
        acc0 = f4fma(acc0, sr[q0], f4add(e0[q0], e1[q0]));
        acc1 = f4fma(acc1, sr[q1], f4add(e0[q1], e1[q1]));
        if (has2) acc2 = f4fma(acc2, sr[q2], f4add(e0[q2], e1[q2]));
    }
    float4* orow = out + (size_t)d * Q4;
    orow[q0] = acc0;
    orow[q1] = acc1;
    if (has2) orow[q2] = acc2;
}

// ---------------------------------------------------------------------------
// K2b: MP round 2 fused with relu + bf16 hi/lo split -> [*][KP] (tail zeroed).
// ---------------------------------------------------------------------------
__global__ __launch_bounds__(256) void k_mp_gather_rs(
        const int* __restrict__ bsrc, const int* __restrict__ battr,
        const int* __restrict__ atom,
        const int* __restrict__ offsets, const int* __restrict__ counts,
        const int* __restrict__ edge_list,
        const float4* __restrict__ Wbt, const float4* __restrict__ Wbai,
        const float4* __restrict__ Wsla, const float4* __restrict__ Wsl,
        const float4* __restrict__ in,
        ushortT* __restrict__ hi, ushortT* __restrict__ lo, int N) {
    int wid  = (int)((blockIdx.x * blockDim.x + threadIdx.x) >> 6);
    int lane = threadIdx.x & 63;
    if (wid >= N) return;
    int d = wid;
    int q0 = lane, q1 = lane + 64, q2 = lane + 128;
    bool has2 = (q2 < Q4);

    const float4* slA = Wsla + atom[d * 5] * Q4;
    const float4* inr = in + (size_t)d * Q4;
    float4 acc0 = make_float4(0, 0, 0, 0), acc1 = acc0, acc2 = acc0;
    acc0 = f4fma(acc0, inr[q0], f4add(slA[q0], Wsl[q0]));
    acc1 = f4fma(acc1, inr[q1], f4add(slA[q1], Wsl[q1]));
    if (has2) acc2 = f4fma(acc2, inr[q2], f4add(slA[q2], Wsl[q2]));

    int start = offsets[d], cnt = counts[d];
    for (int k = 0; k < cnt; k++) {
        int eid = edge_list[start + k];
        int s   = bsrc[eid];
        int t0  = battr[eid * 2 + 0];
        int t1  = battr[eid * 2 + 1];
        const float4* e0 = Wbt  + t0 * Q4;
        const float4* e1 = Wbai + t1 * Q4;
        const float4* sr = in + (size_t)s * Q4;
        acc0 = f4fma(acc0, sr[q0], f4add(e0[q0], e1[q0]));
        acc1 = f4fma(acc1, sr[q1], f4add(e0[q1], e1[q1]));
        if (has2) acc2 = f4fma(acc2, sr[q2], f4add(e0[q2], e1[q2]));
    }
    size_t rb = (size_t)d * KP;
    {
        float v[4] = {acc0.x, acc0.y, acc0.z, acc0.w};
        short4v h4, l4;
#pragma unroll
        for (int j = 0; j < 4; j++) {
            float x = fmaxf(v[j], 0.f);
            ushortT hh = bf16_rne(x);
            h4[j] = (short)hh; l4[j] = (short)bf16_rne(x - bf16_to_f(hh));
        }
        *(short4v*)(hi + rb + q0 * 4) = h4;
        *(short4v*)(lo + rb + q0 * 4) = l4;
    }
    {
        float v[4] = {acc1.x, acc1.y, acc1.z, acc1.w};
        short4v h4, l4;
#pragma unroll
        for (int j = 0; j < 4; j++) {
            float x = fmaxf(v[j], 0.f);
            ushortT hh = bf16_rne(x);
            h4[j] = (short)hh; l4[j] = (short)bf16_rne(x - bf16_to_f(hh));
        }
        *(short4v*)(hi + rb + q1 * 4) = h4;
        *(short4v*)(lo + rb + q1 * 4) = l4;
    }
    if (has2) {
        float v[4] = {acc2.x, acc2.y, acc2.z, acc2.w};
        short4v h4, l4;
#pragma unroll
        for (int j = 0; j < 4; j++) {
            float x = fmaxf(v[j], 0.f);
            ushortT hh = bf16_rne(x);
            h4[j] = (short)hh; l4[j] = (short)bf16_rne(x - bf16_to_f(hh));
        }
        *(short4v*)(hi + rb + q2 * 4) = h4;
        *(short4v*)(lo + rb + q2 * 4) = l4;
    }
    if (lane == 22) {      // zero K-pad cols 600..607
        short8 z = {0, 0, 0, 0, 0, 0, 0, 0};
        *(short8*)(hi + rb + 600) = z;
        *(short8*)(lo + rb + 600) = z;
    }
}

// ---------------------------------------------------------------------------
// Weight split to FRAGMENT-INTERLEAVED layout: tile (cb, kc) = 1 KB, lane l
// holds W[col=cb*16+(l&15)][k8=(l>>4)] as short8. hi/lo bf16 split.
// ---------------------------------------------------------------------------
__global__ void k_split_w_frag(const float* __restrict__ src,
                               short8* __restrict__ dhi, short8* __restrict__ dlo,
                               int rows_in, int cb_count) {
    int idx = blockIdx.x * blockDim.x + threadIdx.x;
    int total = cb_count * 19 * 64;
    if (idx >= total) return;
    int lane = idx & 63;
    int tile = idx >> 6;
    int cb = tile / 19, kc = tile - cb * 19;
    int col = cb * 16 + (lane & 15);
    int k0  = kc * 32 + (lane >> 4) * 8;
    short8 h, l;
#pragma unroll
    for (int j = 0; j < 8; j++) {
        int k = k0 + j;
        float x = (col < rows_in && k < 600) ? src[(size_t)col * 600 + k] : 0.f;
        ushortT hh = bf16_rne(x);
        h[j] = (short)hh;
        l[j] = (short)bf16_rne(x - bf16_to_f(hh));
    }
    dhi[idx] = h;
    dlo[idx] = l;
}

// ---------------------------------------------------------------------------
// MFMA GEMM core v4 (bf16x3): 128x128 tile, BK=32, 4 waves.
// A hi/lo staged via global_load_lds into fragment-order LDS, double-buffered
// (32 KB total). B loaded direct global->reg from fragment-interleaved weights
// (L2-hot); B loads issued BEFORE the A-GLDS of the next chunk so the
// compiler's vmcnt wait for B does not drain the staging queue.
// ---------------------------------------------------------------------------
__device__ __forceinline__ void gemm_core_v4(
        const ushortT* __restrict__ Ahi, const ushortT* __restrict__ Alo,
        const short8* __restrict__ Wfh, const short8* __restrict__ Wfl,
        int row0, int cb0, f32x4 acc[4][4], short8* sbuf) {
    const int t = threadIdx.x;
    const int w = t >> 6, l = t & 63;
    const int wr = w >> 1, wc = w & 1;
    const int fr  = l & 15;
    const int ks_ = l >> 4;

#define STAGE(nb, kc)                                                          \
    {                                                                          \
        int k0 = (kc) * 32 + ks_ * 8;                                          \
        _Pragma("unroll")                                                      \
        for (int r = 0; r < 2; r++) {                                          \
            int rb = 2 * w + r;                                                \
            GLDS(Ahi + (size_t)(row0 + rb * 16 + fr) * KP + k0,                \
                 &sbuf[(nb) * 1024 + 0 * 512 + rb * 64]);                      \
            GLDS(Alo + (size_t)(row0 + rb * 16 + fr) * KP + k0,                \
                 &sbuf[(nb) * 1024 + 1 * 512 + rb * 64]);                      \
        }                                                                      \
    }

#define LOADB(kc)                                                              \
    short8 bh[4], bl[4];                                                       \
    _Pragma("unroll")                                                          \
    for (int j = 0; j < 4; j++) {                                              \
        int tIdx = ((cb0 + wc * 4 + j) * 19 + (kc)) * 64 + l;                  \
        bh[j] = Wfh[tIdx];                                                     \
        bl[j] = Wfl[tIdx];                                                     \
    }

#define COMPUTE(buf)                                                           \
    _Pragma("unroll")                                                          \
    for (int i = 0; i < 4; i++) {                                              \
        short8 ah = sbuf[(buf) * 1024 + 0 * 512 + (wr * 4 + i) * 64 + l];      \
        short8 al = sbuf[(buf) * 1024 + 1 * 512 + (wr * 4 + i) * 64 + l];      \
        _Pragma("unroll")                                                      \
        for (int j = 0; j < 4; j++) {                                          \
            acc[i][j] = __builtin_amdgcn_mfma_f32_16x16x32_bf16(ah, bh[j], acc[i][j], 0, 0, 0); \
            acc[i][j] = __builtin_amdgcn_mfma_f32_16x16x32_bf16(ah, bl[j], acc[i][j], 0, 0, 0); \
            acc[i][j] = __builtin_amdgcn_mfma_f32_16x16x32_bf16(al, bh[j], acc[i][j], 0, 0, 0); \
        }                                                                      \
    }

    STAGE(0, 0);
    __syncthreads();
    for (int kc = 0; kc < 18; kc += 2) {
        {   // body A: compute kc from buf0
            LOADB(kc);
            STAGE(1, kc + 1);
            COMPUTE(0);
        }
        __syncthreads();
        {   // body B: compute kc+1 from buf1
            LOADB(kc + 1);
            if (kc + 2 <= 18) STAGE(0, kc + 2);
            COMPUTE(1);
        }
        __syncthreads();
    }
    {   // kc = 18, buf0
        LOADB(18);
        COMPUTE(0);
    }
#undef STAGE
#undef LOADB
#undef COMPUTE
}

// m204 bijective XCD swizzle: consecutive logical wgids land on one XCD, so
// the ncb column-blocks of one row-strip share A through that XCD's L2.
__device__ __forceinline__ void decode_wg(int ncb, int& rowblk, int& colblk) {
    int nwg  = gridDim.x;
    int orig = blockIdx.x;
    int q = nwg >> 3, r = nwg & 7;
    int xcd = orig & 7, rank = orig >> 3;
    int wgid = (xcd < r ? xcd * (q + 1) : r * (q + 1) + (xcd - r) * q) + rank;
    rowblk = wgid / ncb;
    colblk = wgid - rowblk * ncb;
}

// GEMM1: H = relu(A @ W1^T + b1) -> Hhi/Hlo [Npad][608].  grid: Mb*5 (1-D)
__global__ __launch_bounds__(256) void k_gemm1(
        const ushortT* __restrict__ Ahi, const ushortT* __restrict__ Alo,
        const short8* __restrict__ Wfh, const short8* __restrict__ Wfl,
        const float* __restrict__ b1,
        ushortT* __restrict__ Hhi, ushortT* __restrict__ Hlo, int N) {
    __shared__ short8 sbuf[2048];   // 32 KB
    int rowblk, colblk;
    decode_wg(5, rowblk, colblk);
    int row0 = rowblk * 128;
    int col0 = colblk * 128;
    f32x4 acc[4][4];
#pragma unroll
    for (int i = 0; i < 4; i++)
#pragma unroll
        for (int j = 0; j < 4; j++) acc[i][j] = f32x4{0.f, 0.f, 0.f, 0.f};
    gemm_core_v4(Ahi, Alo, Wfh, Wfl, row0, colblk * 8, acc, sbuf);

    int t = threadIdx.x, w = t >> 6, l = t & 63;
    int wr = w >> 1, wc = w & 1, fr = l & 15, fq = l >> 4;
#pragma unroll
    for (int i = 0; i < 4; i++) {
        int row_b = row0 + wr * 64 + i * 16 + fq * 4;
#pragma unroll
        for (int j = 0; j < 4; j++) {
            int col = col0 + wc * 64 + j * 16 + fr;
            if (col < 600) {
                float bias = b1[col];
#pragma unroll
                for (int r = 0; r < 4; r++) {
                    int row = row_b + r;
                    if (row < N) {
                        float x = fmaxf(acc[i][j][r] + bias, 0.f);
                        ushortT hh = bf16_rne(x);
                        Hhi[(size_t)row * KP + col] = hh;
                        Hlo[(size_t)row * KP + col] = bf16_rne(x - bf16_to_f(hh));
                    }
                }
            } else if (col < KP) {
#pragma unroll
                for (int r = 0; r < 4; r++) {
                    int row = row_b + r;
                    if (row < N) {
                        Hhi[(size_t)row * KP + col] = 0;
                        Hlo[(size_t)row * KP + col] = 0;
                    }
                }
            }
        }
    }
}

// GEMM2: energy += sum_col relu(H @ W2^T + b2) * W3.  grid: Mb*3 (1-D)
__global__ __launch_bounds__(256) void k_gemm2(
        const ushortT* __restrict__ Ahi, const ushortT* __restrict__ Alo,
        const short8* __restrict__ Wfh, const short8* __restrict__ Wfl,
        const float* __restrict__ b2, const float* __restrict__ W3,
        float* __restrict__ energy, int N) {
    __shared__ short8 sbuf[2048];   // 32 KB, reused for the row-reduce
    int rowblk, colblk;
    decode_wg(3, rowblk, colblk);
    int row0 = rowblk * 128;
    int col0 = colblk * 128;
    f32x4 acc[4][4];
#pragma unroll
    for (int i = 0; i < 4; i++)
#pragma unroll
        for (int j = 0; j < 4; j++) acc[i][j] = f32x4{0.f, 0.f, 0.f, 0.f};
    gemm_core_v4(Ahi, Alo, Wfh, Wfl, row0, colblk * 8, acc, sbuf);
    __syncthreads();
    float* sE = (float*)sbuf;

    int t = threadIdx.x, w = t >> 6, l = t & 63;
    int wr = w >> 1, wc = w & 1, fr = l & 15, fq = l >> 4;
    if (t < 128) sE[t] = 0.f;
    __syncthreads();
#pragma unroll
    for (int i = 0; i < 4; i++) {
        float p[4] = {0.f, 0.f, 0.f, 0.f};
#pragma unroll
        for (int j = 0; j < 4; j++) {
            int col = col0 + wc * 64 + j * 16 + fr;
            if (col < 300) {
                float bias = b2[col];
                float wv   = W3[col];
#pragma unroll
                for (int r = 0; r < 4; r++)
                    p[r] += fmaxf(acc[i][j][r] + bias, 0.f) * wv;
            }
        }
#pragma unroll
        for (int r = 0; r < 4; r++) {
            float v = p[r];
            v += __shfl_xor(v, 1, 64);
            v += __shfl_xor(v, 2, 64);
            v += __shfl_xor(v, 4, 64);
            v += __shfl_xor(v, 8, 64);
            p[r] = v;
        }
        if (fr == 0) {
#pragma unroll
            for (int r = 0; r < 4; r++)
                atomicAdd(&sE[wr * 64 + i * 16 + fq * 4 + r], p[r]);
        }
    }
    __syncthreads();
    if (t < 128) {
        int row = row0 + t;
        if (row < N) atomicAdd(&energy[row], sE[t]);
    }
}

// ---------------------------------------------------------------------------
// K5: per-graph pool
// ---------------------------------------------------------------------------
__global__ void k_pool(const float* __restrict__ energy, const int* __restrict__ batch,
                       float* __restrict__ dg, int N) {
    int i = blockIdx.x * blockDim.x + threadIdx.x;
    if (i < N) atomicAdd(&dg[batch[i]], energy[i]);
}

extern "C" void kernel_launch(void* const* d_in, const int* in_sizes, int n_in,
                              void* d_out, int out_size, void* d_ws, size_t ws_size,
                              hipStream_t stream) {
    const int* atom       = (const int*)d_in[0];
    const int* bond_index = (const int*)d_in[1];
    const int* bond_attr  = (const int*)d_in[2];
    const int* batch      = (const int*)d_in[3];
    const float* Wa   = (const float*)d_in[4];
    const float* Wh   = (const float*)d_in[5];
    const float* War  = (const float*)d_in[6];
    const float* Wc   = (const float*)d_in[7];
    const float* Wch  = (const float*)d_in[8];
    const float* Wbt  = (const float*)d_in[9];
    const float* Wbai = (const float*)d_in[10];
    const float* Wsla = (const float*)d_in[11];
    const float* Wsl  = (const float*)d_in[12];
    const float* W1   = (const float*)d_in[13];
    const float* b1   = (const float*)d_in[14];
    const float* W2   = (const float*)d_in[15];
    const float* b2   = (const float*)d_in[16];
    const float* W3   = (const float*)d_in[17];

    int N = in_sizes[0] / 5;   // 50000
    int E = in_sizes[1] / 2;   // 100000
    int Mb = (N + 127) / 128;  // 391
    int Npad = Mb * 128;       // 50048

    size_t regionBytes = (size_t)Npad * KP * 4;
    char* base = (char*)d_ws;
    float* nodeA = (float*)base;                       // region0: embed out, mp1 in
    float* nodeB = (float*)(base + regionBytes);       // region1: mp1 out, mp2 in
    // region0 reused: Ahi/Alo (mp2 out, gemm1 in); region1 reused: Hhi/Hlo
    ushortT* Ahi = (ushortT*)nodeA;
    ushortT* Alo = Ahi + (size_t)Npad * KP;
    ushortT* Hhi = (ushortT*)nodeB;
    ushortT* Hlo = Hhi + (size_t)Npad * KP;
    // tail scratch
    char* tail = base + 2 * regionBytes;
    float* energy  = (float*)tail;
    int* counts    = (int*)(energy + N);
    int* offsets   = counts + N;
    int* cursor    = offsets + N;
    int* edge_list = cursor + N;
    short8* W1fh   = (short8*)(edge_list + E);         // 40*19*64 tiles
    short8* W1fl   = W1fh + 40 * 19 * 64;
    short8* W2fh   = W1fl + 40 * 19 * 64;              // 24*19*64 tiles
    short8* W2fl   = W2fh + 24 * 19 * 64;

    const int* bsrc = bond_index;
    const int* bdst = bond_index + E;

    // CSR build (dst -> edges)
    hipMemsetAsync(counts, 0, (size_t)N * sizeof(int), stream);
    k_hist<<<(E + 255) / 256, 256, 0, stream>>>(bdst, counts, E);
    k_scan<<<1, 1024, 0, stream>>>(counts, offsets, cursor, N);
    k_scatter<<<(E + 255) / 256, 256, 0, stream>>>(bdst, cursor, edge_list, E);

    // weight splits to fragment-interleaved layout
    k_split_w_frag<<<(40 * 19 * 64 + 255) / 256, 256, 0, stream>>>(W1, W1fh, W1fl, 600, 40);
    k_split_w_frag<<<(24 * 19 * 64 + 255) / 256, 256, 0, stream>>>(W2, W2fh, W2fl, 300, 24);

    // K1: node embedding -> nodeA
    {
        int total = N * Q4;
        k_node_embed<<<(total + 255) / 256, 256, 0, stream>>>(
            atom, (const float4*)Wa, (const float4*)Wh, (const float4*)War,
            (const float4*)Wc, (const float4*)Wch, (float4*)nodeA, N);
    }

    int mpblocks = (N * 64 + 255) / 256;
    // round 1: nodeA -> nodeB (fp32)
    k_mp_gather<<<mpblocks, 256, 0, stream>>>(bsrc, bond_attr, atom,
        offsets, counts, edge_list,
        (const float4*)Wbt, (const float4*)Wbai, (const float4*)Wsla, (const float4*)Wsl,
        (const float4*)nodeA, (float4*)nodeB, N);

    // zero A pad rows (region0; safe now that nodeA is dead)
    hipMemsetAsync(Ahi + (size_t)N * KP, 0, (size_t)(Npad - N) * KP * 2, stream);
    hipMemsetAsync(Alo + (size_t)N * KP, 0, (size_t)(Npad - N) * KP * 2, stream);

    // round 2 fused with relu+split: nodeB -> Ahi/Alo (region0)
    k_mp_gather_rs<<<mpblocks, 256, 0, stream>>>(bsrc, bond_attr, atom,
        offsets, counts, edge_list,
        (const float4*)Wbt, (const float4*)Wbai, (const float4*)Wsla, (const float4*)Wsl,
        (const float4*)nodeB, Ahi, Alo, N);

    // GEMM1: Ahi/Alo x W1 -> Hhi/Hlo (region1; nodeB dead)
    k_gemm1<<<Mb * 5, 256, 0, stream>>>(Ahi, Alo, W1fh, W1fl, b1, Hhi, Hlo, N);

    // GEMM2: Hhi/Hlo x W2 (+b2, W3) -> energy (atomic accumulate)
    hipMemsetAsync(energy, 0, (size_t)N * sizeof(float), stream);
    k_gemm2<<<Mb * 3, 256, 0, stream>>>(Hhi, Hlo, W2fh, W2fl, b2, W3, energy, N);

    // pool
    hipMemsetAsync(d_out, 0, (size_t)out_size * sizeof(float), stream);
    k_pool<<<(N + 255) / 256, 256, 0, stream>>>(energy, batch, (float*)d_out, N);
}